// Round 9
// baseline (843.925 us; speedup 1.0000x reference)
//
#include <hip/hip_runtime.h>
#include <hip/hip_bf16.h>

#define NN 50000
#define NE 800000
#define C 128
#define H 16

typedef unsigned int u32;
typedef unsigned short u16;

// ---------- silu + 7 cubic B-spline bases, closed form, NAMED outputs ----------
__device__ __forceinline__ void feat8s(float x, float& s, float& g0, float& g1,
                                       float& g2, float& g3, float& g4, float& g5,
                                       float& g6) {
  s = x / (1.f + __expf(-x));
  float t = (x + 2.5f) * 2.0f;
  float cf = floorf(t);
  int c = (int)cf;
  float u = t - cf;
  float u2 = u * u, u3 = u2 * u;
  const float k6 = 1.f / 6.f;
  float P0 = u3 * k6;
  float P1 = (1.f + 3.f * u + 3.f * u2 - 3.f * u3) * k6;
  float P2 = (4.f - 6.f * u2 + 3.f * u3) * k6;
  float om = 1.f - u;
  float P3 = om * om * om * k6;
  bool valid = (t >= 0.f) && (t < 10.f);
#define SPJ(G, J)                                   \
  {                                                 \
    float b = 0.f;                                  \
    b = (c == (J)) ? P0 : b;                        \
    b = (c == (J) + 1) ? P1 : b;                    \
    b = (c == (J) + 2) ? P2 : b;                    \
    b = (c == (J) + 3) ? P3 : b;                    \
    G = valid ? b : 0.f;                            \
  }
  SPJ(g0, 0) SPJ(g1, 1) SPJ(g2, 2) SPJ(g3, 3) SPJ(g4, 4) SPJ(g5, 5) SPJ(g6, 6)
#undef SPJ
}

__device__ __forceinline__ u16 f2bf(float v) {
  u32 b = __float_as_uint(v);
  return (u16)((b + 0x7fffu + ((b >> 16) & 1u)) >> 16);  // RNE
}

// unpack 8 bf16 (uint4) -> 8 named f32
__device__ __forceinline__ void unpk8(uint4 r, float& w0, float& w1, float& w2,
                                      float& w3, float& w4, float& w5, float& w6,
                                      float& w7) {
  w0 = __uint_as_float(r.x << 16);
  w1 = __uint_as_float(r.x & 0xffff0000u);
  w2 = __uint_as_float(r.y << 16);
  w3 = __uint_as_float(r.y & 0xffff0000u);
  w4 = __uint_as_float(r.z << 16);
  w5 = __uint_as_float(r.z & 0xffff0000u);
  w6 = __uint_as_float(r.w << 16);
  w7 = __uint_as_float(r.w & 0xffff0000u);
}

__device__ __forceinline__ float fma8(float w0, float w1, float w2, float w3,
                                      float w4, float w5, float w6, float w7,
                                      float a0, float a1, float a2, float a3,
                                      float a4, float a5, float a6, float a7,
                                      float acc) {
  acc = fmaf(w0, a0, acc); acc = fmaf(w1, a1, acc);
  acc = fmaf(w2, a2, acc); acc = fmaf(w3, a3, acc);
  acc = fmaf(w4, a4, acc); acc = fmaf(w5, a5, acc);
  acc = fmaf(w6, a6, acc); acc = fmaf(w7, a7, acc);
  return acc;
}

#define RL(x, J) __int_as_float(__builtin_amdgcn_readlane(__float_as_int(x), (J)))
#define REP16(M) M(0) M(1) M(2) M(3) M(4) M(5) M(6) M(7) M(8) M(9) M(10) M(11) M(12) M(13) M(14) M(15)

// ---------- prep: Wt transpose (f32) + bf16 packed KAN weights ----------
__global__ void prep_kernel(const float* __restrict__ W,
                            const float* __restrict__ bw0, const float* __restrict__ sw0,
                            const float* __restrict__ sc0,
                            const float* __restrict__ bw1, const float* __restrict__ sw1,
                            const float* __restrict__ sc1,
                            float* __restrict__ Wt, u16* __restrict__ p0bf,
                            u16* __restrict__ p1bf) {
  int i = blockIdx.x * blockDim.x + threadIdx.x;
  if (i < C * C) {
    int k = i >> 7, o = i & 127;
    Wt[k * C + o] = W[o * C + k];
  }
  if (i < H * C * 8) {
    int of = i >> 3, j = i & 7;
    float v = (j == 0) ? bw0[of] : sw0[of * 7 + (j - 1)] * sc0[of];
    p0bf[i] = f2bf(v);
  }
  if (i < C * H * 8) {
    int of = i >> 3, j = i & 7;
    float v = (j == 0) ? bw1[of] : sw1[of * 7 + (j - 1)] * sc1[of];
    p1bf[i] = f2bf(v);
  }
}

// ---------- in-degree count ----------
__global__ void count_kernel(const int* __restrict__ dst, int* __restrict__ cnt) {
  int e = blockIdx.x * blockDim.x + threadIdx.x;
  if (e < NE) atomicAdd(&cnt[dst[e]], 1);
}

// ---------- hierarchical exclusive scan ----------
__global__ void scan1(const int* __restrict__ cnt, int* __restrict__ excl,
                      int* __restrict__ bsums, int n) {
  int i = blockIdx.x * 256 + threadIdx.x;
  int v = (i < n) ? cnt[i] : 0;
  int lane = threadIdx.x & 63, wid = threadIdx.x >> 6;
  int s = v;
#pragma unroll
  for (int o = 1; o < 64; o <<= 1) {
    int t = __shfl_up(s, o, 64);
    if (lane >= o) s += t;
  }
  __shared__ int wsum[4];
  if (lane == 63) wsum[wid] = s;
  __syncthreads();
  int woff = 0;
  for (int w = 0; w < wid; ++w) woff += wsum[w];
  if (i < n) excl[i] = woff + s - v;
  if (threadIdx.x == 255) bsums[blockIdx.x] = woff + s;
}

__global__ void scan2(int* __restrict__ bsums, int nb) {
  int i = threadIdx.x;
  int v = (i < nb) ? bsums[i] : 0;
  int lane = threadIdx.x & 63, wid = threadIdx.x >> 6;
  int s = v;
#pragma unroll
  for (int o = 1; o < 64; o <<= 1) {
    int t = __shfl_up(s, o, 64);
    if (lane >= o) s += t;
  }
  __shared__ int wsum[4];
  if (lane == 63) wsum[wid] = s;
  __syncthreads();
  int woff = 0;
  for (int w = 0; w < wid; ++w) woff += wsum[w];
  if (i < nb) bsums[i] = woff + s - v;
}

__global__ void scan3(const int* __restrict__ excl, const int* __restrict__ bsums,
                      const int* __restrict__ cnt, int* __restrict__ row_start,
                      float* __restrict__ dinv, int n) {
  int i = blockIdx.x * 256 + threadIdx.x;
  if (i < n) {
    row_start[i] = excl[i] + bsums[blockIdx.x];
    dinv[i] = rsqrtf((float)(cnt[i] + 1));
  }
  if (blockIdx.x == 0 && threadIdx.x == 0) row_start[n] = NE;
}

// ---------- CSR fill; csrw = dinv[src]*dinv[dst] ----------
__global__ void fill_kernel(const int* __restrict__ src, const int* __restrict__ dst,
                            const int* __restrict__ row_start, const float* __restrict__ dinv,
                            int* __restrict__ fillcnt, int* __restrict__ csr,
                            float* __restrict__ csrw) {
  int e = blockIdx.x * blockDim.x + threadIdx.x;
  if (e < NE) {
    int d = dst[e];
    int s = src[e];
    int p = atomicAdd(&fillcnt[d], 1);
    int slot = row_start[d] + p;
    csr[slot] = s;
    csrw[slot] = dinv[s] * dinv[d];
  }
}

// ---------- aggregation ----------
__global__ __launch_bounds__(256, 8) void agg_kernel(
    const float* __restrict__ x, const int* __restrict__ csr,
    const float* __restrict__ csrw, const int* __restrict__ row_start,
    const float* __restrict__ dinv, float* __restrict__ ax) {
  const int c = threadIdx.x & 127;
  const int node = blockIdx.x * 2 + (threadIdx.x >> 7);
  const int e0 = row_start[node], e1 = row_start[node + 1];
  const float dn = dinv[node];
  float a = x[(size_t)node * C + c] * (dn * dn);
  int e = e0;
  for (; e + 4 <= e1; e += 4) {
    const int s0 = csr[e], s1 = csr[e + 1], s2 = csr[e + 2], s3 = csr[e + 3];
    const float w0 = csrw[e], w1 = csrw[e + 1], w2 = csrw[e + 2], w3 = csrw[e + 3];
    a += x[(size_t)s0 * C + c] * w0;
    a += x[(size_t)s1 * C + c] * w1;
    a += x[(size_t)s2 * C + c] * w2;
    a += x[(size_t)s3 * C + c] * w3;
  }
  for (; e < e1; ++e) a += x[(size_t)csr[e] * C + c] * csrw[e];
  ax[(size_t)node * C + c] = a;
}

// ---------- GEMV as tiled GEMM, in-place: h = ax @ W^T ----------
__global__ __launch_bounds__(256) void gemm128(const float* __restrict__ Wt,
                                               float* __restrict__ axh) {
  __shared__ float Xs[64][129];
  __shared__ float Ws[32][132];
  const int tid = threadIdx.x;
  const int n0 = blockIdx.x * 64;
#pragma unroll
  for (int it = 0; it < 8; ++it) {
    int idx = it * 1024 + tid * 4;
    int n = idx >> 7, k = idx & 127;
    float4 v = make_float4(0.f, 0.f, 0.f, 0.f);
    if (n0 + n < NN) v = *(const float4*)&axh[(size_t)(n0 + n) * C + k];
    *(float4*)&Xs[n][k] = v;
  }
  const int nt = tid & 15, ot = tid >> 4;
  float4 accA[4], accB[4];
#pragma unroll
  for (int d = 0; d < 4; ++d) {
    accA[d] = make_float4(0.f, 0.f, 0.f, 0.f);
    accB[d] = make_float4(0.f, 0.f, 0.f, 0.f);
  }
  for (int k0 = 0; k0 < 128; k0 += 32) {
    __syncthreads();
#pragma unroll
    for (int it = 0; it < 4; ++it) {
      int idx = it * 1024 + tid * 4;
      int k = idx >> 7, oo = idx & 127;
      *(float4*)&Ws[k][oo] = *(const float4*)&Wt[(k0 + k) * C + oo];
    }
    __syncthreads();
#pragma unroll
    for (int k = 0; k < 32; ++k) {
      float4 w0 = *(const float4*)&Ws[k][ot * 8];
      float4 w1 = *(const float4*)&Ws[k][ot * 8 + 4];
#pragma unroll
      for (int d = 0; d < 4; ++d) {
        float xv = Xs[nt * 4 + d][k0 + k];
        accA[d].x += xv * w0.x; accA[d].y += xv * w0.y;
        accA[d].z += xv * w0.z; accA[d].w += xv * w0.w;
        accB[d].x += xv * w1.x; accB[d].y += xv * w1.y;
        accB[d].z += xv * w1.z; accB[d].w += xv * w1.w;
      }
    }
  }
#pragma unroll
  for (int d = 0; d < 4; ++d) {
    int node = n0 + nt * 4 + d;
    if (node < NN) {
      *(float4*)&axh[(size_t)node * C + ot * 8] = accA[d];
      *(float4*)&axh[(size_t)node * C + ot * 8 + 4] = accB[d];
    }
  }
}

// ---------- KAN stack v4: 2 nodes/wave, shared unpack, packed butterfly ----------
// r8 was VALU-issue-bound (90% busy). Cuts: (1) packed 16-value butterfly:
// 17 shfl instead of 96, lands h[j=lane&15] in the right lane (no select
// chain); (2) 2 nodes share each unpacked bf16 weight (halves unpack + LDS
// weight reads); (3) sched_barrier(0) per J keeps the live set tiny (r8).
__global__ __launch_bounds__(512) void kanE(
    const float* __restrict__ h, const float* __restrict__ bias,
    const u16* __restrict__ p0bf, const u16* __restrict__ p1bf,
    float* __restrict__ out) {
  __shared__ u32 P0s[8192];   // 32 KB: uint4 record j*128 + f
  __shared__ u32 P1s[8192];   // 32 KB: uint4 record j*128 + o
  const int tid = threadIdx.x;
  {
    const uint4* g0 = (const uint4*)p0bf;
    const uint4* g1 = (const uint4*)p1bf;
    uint4* s0 = (uint4*)P0s;
    uint4* s1 = (uint4*)P1s;
    for (int r = tid; r < 2048; r += 512) {
      s0[r] = g0[r];
      int oo = r >> 4, j = r & 15;
      s1[j * 128 + oo] = g1[r];
    }
  }
  __syncthreads();
  const int o = tid & 63;
  const int wave = tid >> 6;
  const float bLo = bias[o], bHi = bias[o + 64];
  const bool b1 = (o & 1), b2 = (o & 2), b4 = (o & 4), b8 = (o & 8);
  for (int pr = blockIdx.x * 8 + wave; pr < NN / 2; pr += 4096) {
    const int nodeA = pr * 2, nodeB = nodeA + 1;
    float faA0, faA1, faA2, faA3, faA4, faA5, faA6, faA7;
    float fbA0, fbA1, fbA2, fbA3, fbA4, fbA5, fbA6, fbA7;
    float faB0, faB1, faB2, faB3, faB4, faB5, faB6, faB7;
    float fbB0, fbB1, fbB2, fbB3, fbB4, fbB5, fbB6, fbB7;
    feat8s(h[(size_t)nodeA * C + o] + bLo, faA0, faA1, faA2, faA3, faA4, faA5, faA6, faA7);
    feat8s(h[(size_t)nodeA * C + o + 64] + bHi, fbA0, fbA1, fbA2, fbA3, fbA4, fbA5, fbA6, fbA7);
    feat8s(h[(size_t)nodeB * C + o] + bLo, faB0, faB1, faB2, faB3, faB4, faB5, faB6, faB7);
    feat8s(h[(size_t)nodeB * C + o + 64] + bHi, fbB0, fbB1, fbB2, fbB3, fbB4, fbB5, fbB6, fbB7);
    // KAN0 partials for both nodes, shared weight unpack
    float pA[16], pB[16];
#define K0J(J)                                                                 \
    {                                                                          \
      uint4 ra = *(const uint4*)&P0s[(J) * 512 + o * 4];                       \
      uint4 rb = *(const uint4*)&P0s[(J) * 512 + (o + 64) * 4];                \
      float w0, w1, w2, w3, w4, w5, w6, w7, u0, u1, u2, u3, u4, u5, u6, u7;    \
      unpk8(ra, w0, w1, w2, w3, w4, w5, w6, w7);                               \
      unpk8(rb, u0, u1, u2, u3, u4, u5, u6, u7);                               \
      float vA = fma8(w0, w1, w2, w3, w4, w5, w6, w7,                          \
                      faA0, faA1, faA2, faA3, faA4, faA5, faA6, faA7, 0.f);    \
      pA[(J)] = fma8(u0, u1, u2, u3, u4, u5, u6, u7,                           \
                     fbA0, fbA1, fbA2, fbA3, fbA4, fbA5, fbA6, fbA7, vA);      \
      float vB = fma8(w0, w1, w2, w3, w4, w5, w6, w7,                          \
                      faB0, faB1, faB2, faB3, faB4, faB5, faB6, faB7, 0.f);    \
      pB[(J)] = fma8(u0, u1, u2, u3, u4, u5, u6, u7,                           \
                     fbB0, fbB1, fbB2, fbB3, fbB4, fbB5, fbB6, fbB7, vB);      \
      __builtin_amdgcn_sched_barrier(0);                                      \
    }
    REP16(K0J)
#undef K0J
    // packed butterfly: 16 values -> lane o ends with full sum of j = o&15
#define BFLY(P, OUTV)                                                          \
    {                                                                          \
      float q[8], r_[4], s_[2], t_;                                            \
      _Pragma("unroll")                                                        \
      for (int m = 0; m < 8; ++m) {                                            \
        float snd = b1 ? P[2 * m] : P[2 * m + 1];                              \
        float kp  = b1 ? P[2 * m + 1] : P[2 * m];                              \
        q[m] = kp + __shfl_xor(snd, 1, 64);                                    \
      }                                                                        \
      _Pragma("unroll")                                                        \
      for (int m = 0; m < 4; ++m) {                                            \
        float snd = b2 ? q[2 * m] : q[2 * m + 1];                              \
        float kp  = b2 ? q[2 * m + 1] : q[2 * m];                              \
        r_[m] = kp + __shfl_xor(snd, 2, 64);                                   \
      }                                                                        \
      _Pragma("unroll")                                                        \
      for (int m = 0; m < 2; ++m) {                                            \
        float snd = b4 ? r_[2 * m] : r_[2 * m + 1];                            \
        float kp  = b4 ? r_[2 * m + 1] : r_[2 * m];                            \
        s_[m] = kp + __shfl_xor(snd, 4, 64);                                   \
      }                                                                        \
      {                                                                        \
        float snd = b8 ? s_[0] : s_[1];                                        \
        float kp  = b8 ? s_[1] : s_[0];                                        \
        t_ = kp + __shfl_xor(snd, 8, 64);                                      \
      }                                                                        \
      t_ += __shfl_xor(t_, 16, 64);                                            \
      t_ += __shfl_xor(t_, 32, 64);                                            \
      OUTV = t_;                                                               \
    }
    float hA, hB;
    BFLY(pA, hA)
    BFLY(pB, hB)
#undef BFLY
    // lane o holds hidden j = o&15 for both nodes; feats thereof
    float fhA0, fhA1, fhA2, fhA3, fhA4, fhA5, fhA6, fhA7;
    float fhB0, fhB1, fhB2, fhB3, fhB4, fhB5, fhB6, fhB7;
    feat8s(hA, fhA0, fhA1, fhA2, fhA3, fhA4, fhA5, fhA6, fhA7);
    feat8s(hB, fhB0, fhB1, fhB2, fhB3, fhB4, fhB5, fhB6, fhB7);
    // KAN1: broadcast hidden-J feats from lane J; shared weight unpack
    float accLoA = 0.f, accHiA = 0.f, accLoB = 0.f, accHiB = 0.f;
#define K1J(J)                                                                 \
    {                                                                          \
      uint4 ra = *(const uint4*)&P1s[(J) * 512 + o * 4];                       \
      uint4 rb = *(const uint4*)&P1s[(J) * 512 + (o + 64) * 4];                \
      float w0, w1, w2, w3, w4, w5, w6, w7, u0, u1, u2, u3, u4, u5, u6, u7;    \
      unpk8(ra, w0, w1, w2, w3, w4, w5, w6, w7);                               \
      unpk8(rb, u0, u1, u2, u3, u4, u5, u6, u7);                               \
      float qA0 = RL(fhA0, J), qA1 = RL(fhA1, J), qA2 = RL(fhA2, J),           \
            qA3 = RL(fhA3, J), qA4 = RL(fhA4, J), qA5 = RL(fhA5, J),           \
            qA6 = RL(fhA6, J), qA7 = RL(fhA7, J);                              \
      float qB0 = RL(fhB0, J), qB1 = RL(fhB1, J), qB2 = RL(fhB2, J),           \
            qB3 = RL(fhB3, J), qB4 = RL(fhB4, J), qB5 = RL(fhB5, J),           \
            qB6 = RL(fhB6, J), qB7 = RL(fhB7, J);                              \
      accLoA = fma8(w0, w1, w2, w3, w4, w5, w6, w7,                            \
                    qA0, qA1, qA2, qA3, qA4, qA5, qA6, qA7, accLoA);           \
      accHiA = fma8(u0, u1, u2, u3, u4, u5, u6, u7,                            \
                    qA0, qA1, qA2, qA3, qA4, qA5, qA6, qA7, accHiA);           \
      accLoB = fma8(w0, w1, w2, w3, w4, w5, w6, w7,                            \
                    qB0, qB1, qB2, qB3, qB4, qB5, qB6, qB7, accLoB);           \
      accHiB = fma8(u0, u1, u2, u3, u4, u5, u6, u7,                            \
                    qB0, qB1, qB2, qB3, qB4, qB5, qB6, qB7, accHiB);           \
      __builtin_amdgcn_sched_barrier(0);                                      \
    }
    REP16(K1J)
#undef K1J
    out[(size_t)nodeA * C + o] = accLoA;
    out[(size_t)nodeA * C + o + 64] = accHiA;
    out[(size_t)nodeB * C + o] = accLoB;
    out[(size_t)nodeB * C + o + 64] = accHiB;
  }
}

extern "C" void kernel_launch(void* const* d_in, const int* in_sizes, int n_in,
                              void* d_out, int out_size, void* d_ws, size_t ws_size,
                              hipStream_t stream) {
  const float* x   = (const float*)d_in[0];
  const int*   ei  = (const int*)d_in[1];
  const float* gw  = (const float*)d_in[2];
  const float* gb  = (const float*)d_in[3];
  const float* bw0 = (const float*)d_in[4];
  const float* sw0 = (const float*)d_in[5];
  const float* sc0 = (const float*)d_in[6];
  const float* bw1 = (const float*)d_in[7];
  const float* sw1 = (const float*)d_in[8];
  const float* sc1 = (const float*)d_in[9];
  float* out = (float*)d_out;

  char* p = (char*)d_ws;
  float* Wt = (float*)p;      p += C * C * 4;
  u16* p0bf = (u16*)p;        p += H * C * 8 * 2;
  u16* p1bf = (u16*)p;        p += C * H * 8 * 2;
  float* dinv = (float*)p;    p += NN * 4;
  int* cnt = (int*)p;         p += NN * 4;       // cnt+fillcnt adjacent:
  int* fillcnt = (int*)p;     p += NN * 4;       // one memset covers both
  int* excl = (int*)p;        p += NN * 4;
  int* bsums = (int*)p;       p += 256 * 4;
  int* row_start = (int*)p;   p += (NN + 4) * 4;
  int* csr = (int*)p;         p += (size_t)NE * 4;
  float* csrw = (float*)p;    p += (size_t)NE * 4;
  float* axh = (float*)p;     p += (size_t)NN * C * 4;

  const int* src = ei;
  const int* dst = ei + NE;

  hipMemsetAsync(cnt, 0, 2 * NN * 4, stream);

  prep_kernel<<<64, 256, 0, stream>>>(gw, bw0, sw0, sc0, bw1, sw1, sc1, Wt, p0bf, p1bf);
  count_kernel<<<(NE + 255) / 256, 256, 0, stream>>>(dst, cnt);
  scan1<<<196, 256, 0, stream>>>(cnt, excl, bsums, NN);
  scan2<<<1, 256, 0, stream>>>(bsums, 196);
  scan3<<<196, 256, 0, stream>>>(excl, bsums, cnt, row_start, dinv, NN);
  fill_kernel<<<(NE + 255) / 256, 256, 0, stream>>>(src, dst, row_start, dinv, fillcnt, csr, csrw);
  agg_kernel<<<NN / 2, 256, 0, stream>>>(x, csr, csrw, row_start, dinv, axh);
  gemm128<<<(NN + 63) / 64, 256, 0, stream>>>(Wt, axh);
  kanE<<<512, 512, 0, stream>>>(axh, gb, p0bf, p1bf, out);
}

// Round 10
// 312.172 us; speedup vs baseline: 2.7034x; 2.7034x over previous
//
#include <hip/hip_runtime.h>

#define NN 50000
#define NE 800000
#define C 128
#define H 16

typedef unsigned int u32;
typedef unsigned short u16;

// ---------- silu + 7 cubic B-spline bases, closed form, NAMED outputs ----------
__device__ __forceinline__ void feat8s(float x, float& s, float& g0, float& g1,
                                       float& g2, float& g3, float& g4, float& g5,
                                       float& g6) {
  s = x / (1.f + __expf(-x));
  float t = (x + 2.5f) * 2.0f;
  float cf = floorf(t);
  int c = (int)cf;
  float u = t - cf;
  float u2 = u * u, u3 = u2 * u;
  const float k6 = 1.f / 6.f;
  float P0 = u3 * k6;
  float P1 = (1.f + 3.f * u + 3.f * u2 - 3.f * u3) * k6;
  float P2 = (4.f - 6.f * u2 + 3.f * u3) * k6;
  float om = 1.f - u;
  float P3 = om * om * om * k6;
  bool valid = (t >= 0.f) && (t < 10.f);
#define SPJ(G, J)                                   \
  {                                                 \
    float b = 0.f;                                  \
    b = (c == (J)) ? P0 : b;                        \
    b = (c == (J) + 1) ? P1 : b;                    \
    b = (c == (J) + 2) ? P2 : b;                    \
    b = (c == (J) + 3) ? P3 : b;                    \
    G = valid ? b : 0.f;                            \
  }
  SPJ(g0, 0) SPJ(g1, 1) SPJ(g2, 2) SPJ(g3, 3) SPJ(g4, 4) SPJ(g5, 5) SPJ(g6, 6)
#undef SPJ
}

__device__ __forceinline__ u16 f2bf(float v) {
  u32 b = __float_as_uint(v);
  return (u16)((b + 0x7fffu + ((b >> 16) & 1u)) >> 16);  // RNE
}

// unpack 8 bf16 (uint4) -> 8 named f32
__device__ __forceinline__ void unpk8(uint4 r, float& w0, float& w1, float& w2,
                                      float& w3, float& w4, float& w5, float& w6,
                                      float& w7) {
  w0 = __uint_as_float(r.x << 16);
  w1 = __uint_as_float(r.x & 0xffff0000u);
  w2 = __uint_as_float(r.y << 16);
  w3 = __uint_as_float(r.y & 0xffff0000u);
  w4 = __uint_as_float(r.z << 16);
  w5 = __uint_as_float(r.z & 0xffff0000u);
  w6 = __uint_as_float(r.w << 16);
  w7 = __uint_as_float(r.w & 0xffff0000u);
}

__device__ __forceinline__ float fma8(float w0, float w1, float w2, float w3,
                                      float w4, float w5, float w6, float w7,
                                      float a0, float a1, float a2, float a3,
                                      float a4, float a5, float a6, float a7,
                                      float acc) {
  acc = fmaf(w0, a0, acc); acc = fmaf(w1, a1, acc);
  acc = fmaf(w2, a2, acc); acc = fmaf(w3, a3, acc);
  acc = fmaf(w4, a4, acc); acc = fmaf(w5, a5, acc);
  acc = fmaf(w6, a6, acc); acc = fmaf(w7, a7, acc);
  return acc;
}

#define RL(x, J) __int_as_float(__builtin_amdgcn_readlane(__float_as_int(x), (J)))
#define REP16(M) M(0) M(1) M(2) M(3) M(4) M(5) M(6) M(7) M(8) M(9) M(10) M(11) M(12) M(13) M(14) M(15)

// ---------- prep: Wt transpose (f32) + bf16 packed KAN weights ----------
__global__ void prep_kernel(const float* __restrict__ W,
                            const float* __restrict__ bw0, const float* __restrict__ sw0,
                            const float* __restrict__ sc0,
                            const float* __restrict__ bw1, const float* __restrict__ sw1,
                            const float* __restrict__ sc1,
                            float* __restrict__ Wt, u16* __restrict__ p0bf,
                            u16* __restrict__ p1bf) {
  int i = blockIdx.x * blockDim.x + threadIdx.x;
  if (i < C * C) {
    int k = i >> 7, o = i & 127;
    Wt[k * C + o] = W[o * C + k];
  }
  if (i < H * C * 8) {
    int of = i >> 3, j = i & 7;
    float v = (j == 0) ? bw0[of] : sw0[of * 7 + (j - 1)] * sc0[of];
    p0bf[i] = f2bf(v);
  }
  if (i < C * H * 8) {
    int of = i >> 3, j = i & 7;
    float v = (j == 0) ? bw1[of] : sw1[of * 7 + (j - 1)] * sc1[of];
    p1bf[i] = f2bf(v);
  }
}

// ---------- in-degree count ----------
__global__ void count_kernel(const int* __restrict__ dst, int* __restrict__ cnt) {
  int e = blockIdx.x * blockDim.x + threadIdx.x;
  if (e < NE) atomicAdd(&cnt[dst[e]], 1);
}

// ---------- hierarchical exclusive scan ----------
__global__ void scan1(const int* __restrict__ cnt, int* __restrict__ excl,
                      int* __restrict__ bsums, int n) {
  int i = blockIdx.x * 256 + threadIdx.x;
  int v = (i < n) ? cnt[i] : 0;
  int lane = threadIdx.x & 63, wid = threadIdx.x >> 6;
  int s = v;
#pragma unroll
  for (int o = 1; o < 64; o <<= 1) {
    int t = __shfl_up(s, o, 64);
    if (lane >= o) s += t;
  }
  __shared__ int wsum[4];
  if (lane == 63) wsum[wid] = s;
  __syncthreads();
  int woff = 0;
  for (int w = 0; w < wid; ++w) woff += wsum[w];
  if (i < n) excl[i] = woff + s - v;
  if (threadIdx.x == 255) bsums[blockIdx.x] = woff + s;
}

__global__ void scan2(int* __restrict__ bsums, int nb) {
  int i = threadIdx.x;
  int v = (i < nb) ? bsums[i] : 0;
  int lane = threadIdx.x & 63, wid = threadIdx.x >> 6;
  int s = v;
#pragma unroll
  for (int o = 1; o < 64; o <<= 1) {
    int t = __shfl_up(s, o, 64);
    if (lane >= o) s += t;
  }
  __shared__ int wsum[4];
  if (lane == 63) wsum[wid] = s;
  __syncthreads();
  int woff = 0;
  for (int w = 0; w < wid; ++w) woff += wsum[w];
  if (i < nb) bsums[i] = woff + s - v;
}

__global__ void scan3(const int* __restrict__ excl, const int* __restrict__ bsums,
                      const int* __restrict__ cnt, int* __restrict__ row_start,
                      float* __restrict__ dinv, int n) {
  int i = blockIdx.x * 256 + threadIdx.x;
  if (i < n) {
    row_start[i] = excl[i] + bsums[blockIdx.x];
    dinv[i] = rsqrtf((float)(cnt[i] + 1));
  }
  if (blockIdx.x == 0 && threadIdx.x == 0) row_start[n] = NE;
}

// ---------- CSR fill; csrw = dinv[src]*dinv[dst] ----------
__global__ void fill_kernel(const int* __restrict__ src, const int* __restrict__ dst,
                            const int* __restrict__ row_start, const float* __restrict__ dinv,
                            int* __restrict__ fillcnt, int* __restrict__ csr,
                            float* __restrict__ csrw) {
  int e = blockIdx.x * blockDim.x + threadIdx.x;
  if (e < NE) {
    int d = dst[e];
    int s = src[e];
    int p = atomicAdd(&fillcnt[d], 1);
    int slot = row_start[d] + p;
    csr[slot] = s;
    csrw[slot] = dinv[s] * dinv[d];
  }
}

// ---------- aggregation ----------
__global__ __launch_bounds__(256, 8) void agg_kernel(
    const float* __restrict__ x, const int* __restrict__ csr,
    const float* __restrict__ csrw, const int* __restrict__ row_start,
    const float* __restrict__ dinv, float* __restrict__ ax) {
  const int c = threadIdx.x & 127;
  const int node = blockIdx.x * 2 + (threadIdx.x >> 7);
  const int e0 = row_start[node], e1 = row_start[node + 1];
  const float dn = dinv[node];
  float a = x[(size_t)node * C + c] * (dn * dn);
  int e = e0;
  for (; e + 4 <= e1; e += 4) {
    const int s0 = csr[e], s1 = csr[e + 1], s2 = csr[e + 2], s3 = csr[e + 3];
    const float w0 = csrw[e], w1 = csrw[e + 1], w2 = csrw[e + 2], w3 = csrw[e + 3];
    a += x[(size_t)s0 * C + c] * w0;
    a += x[(size_t)s1 * C + c] * w1;
    a += x[(size_t)s2 * C + c] * w2;
    a += x[(size_t)s3 * C + c] * w3;
  }
  for (; e < e1; ++e) a += x[(size_t)csr[e] * C + c] * csrw[e];
  ax[(size_t)node * C + c] = a;
}

// ---------- GEMV as tiled GEMM, in-place: h = ax @ W^T ----------
__global__ __launch_bounds__(256) void gemm128(const float* __restrict__ Wt,
                                               float* __restrict__ axh) {
  __shared__ float Xs[64][129];
  __shared__ float Ws[32][132];
  const int tid = threadIdx.x;
  const int n0 = blockIdx.x * 64;
#pragma unroll
  for (int it = 0; it < 8; ++it) {
    int idx = it * 1024 + tid * 4;
    int n = idx >> 7, k = idx & 127;
    float4 v = make_float4(0.f, 0.f, 0.f, 0.f);
    if (n0 + n < NN) v = *(const float4*)&axh[(size_t)(n0 + n) * C + k];
    *(float4*)&Xs[n][k] = v;
  }
  const int nt = tid & 15, ot = tid >> 4;
  float4 accA[4], accB[4];
#pragma unroll
  for (int d = 0; d < 4; ++d) {
    accA[d] = make_float4(0.f, 0.f, 0.f, 0.f);
    accB[d] = make_float4(0.f, 0.f, 0.f, 0.f);
  }
  for (int k0 = 0; k0 < 128; k0 += 32) {
    __syncthreads();
#pragma unroll
    for (int it = 0; it < 4; ++it) {
      int idx = it * 1024 + tid * 4;
      int k = idx >> 7, oo = idx & 127;
      *(float4*)&Ws[k][oo] = *(const float4*)&Wt[(k0 + k) * C + oo];
    }
    __syncthreads();
#pragma unroll
    for (int k = 0; k < 32; ++k) {
      float4 w0 = *(const float4*)&Ws[k][ot * 8];
      float4 w1 = *(const float4*)&Ws[k][ot * 8 + 4];
#pragma unroll
      for (int d = 0; d < 4; ++d) {
        float xv = Xs[nt * 4 + d][k0 + k];
        accA[d].x += xv * w0.x; accA[d].y += xv * w0.y;
        accA[d].z += xv * w0.z; accA[d].w += xv * w0.w;
        accB[d].x += xv * w1.x; accB[d].y += xv * w1.y;
        accB[d].z += xv * w1.z; accB[d].w += xv * w1.w;
      }
    }
  }
#pragma unroll
  for (int d = 0; d < 4; ++d) {
    int node = n0 + nt * 4 + d;
    if (node < NN) {
      *(float4*)&axh[(size_t)node * C + ot * 8] = accA[d];
      *(float4*)&axh[(size_t)node * C + ot * 8 + 4] = accB[d];
    }
  }
}

// ---------- kan0: h -> hid[NN][16]. 2 nodes/wave, shared unpack, packed BFLY ----------
// Small live set (no K1 state): feats die before butterfly; named scalars only.
__global__ __launch_bounds__(512) void kan0(
    const float* __restrict__ h, const float* __restrict__ bias,
    const u16* __restrict__ p0bf, float* __restrict__ hid) {
  __shared__ u32 P0s[8192];   // 32 KB: uint4 record J*128 + f
  const int tid = threadIdx.x;
  {
    const uint4* g0 = (const uint4*)p0bf;
    uint4* s0 = (uint4*)P0s;
    for (int r = tid; r < 2048; r += 512) s0[r] = g0[r];
  }
  __syncthreads();
  const int o = tid & 63;
  const int wave = tid >> 6;
  const float bLo = bias[o], bHi = bias[o + 64];
  const bool b1 = (o & 1), b2 = (o & 2), b4 = (o & 4), b8 = (o & 8);
  for (int pr = blockIdx.x * 8 + wave; pr < NN / 2; pr += 4096) {
    const int nodeA = pr * 2, nodeB = nodeA + 1;
    float faA0, faA1, faA2, faA3, faA4, faA5, faA6, faA7;
    float fbA0, fbA1, fbA2, fbA3, fbA4, fbA5, fbA6, fbA7;
    float faB0, faB1, faB2, faB3, faB4, faB5, faB6, faB7;
    float fbB0, fbB1, fbB2, fbB3, fbB4, fbB5, fbB6, fbB7;
    feat8s(h[(size_t)nodeA * C + o] + bLo, faA0, faA1, faA2, faA3, faA4, faA5, faA6, faA7);
    feat8s(h[(size_t)nodeA * C + o + 64] + bHi, fbA0, fbA1, fbA2, fbA3, fbA4, fbA5, fbA6, fbA7);
    feat8s(h[(size_t)nodeB * C + o] + bLo, faB0, faB1, faB2, faB3, faB4, faB5, faB6, faB7);
    feat8s(h[(size_t)nodeB * C + o + 64] + bHi, fbB0, fbB1, fbB2, fbB3, fbB4, fbB5, fbB6, fbB7);
    // KAN0 partials, shared weight unpack, NAMED p-scalars
#define K0J(J)                                                                 \
    float pA##J, pB##J;                                                        \
    {                                                                          \
      uint4 ra = *(const uint4*)&P0s[(J) * 512 + o * 4];                       \
      uint4 rb = *(const uint4*)&P0s[(J) * 512 + (o + 64) * 4];                \
      float w0, w1, w2, w3, w4, w5, w6, w7, u0, u1, u2, u3, u4, u5, u6, u7;    \
      unpk8(ra, w0, w1, w2, w3, w4, w5, w6, w7);                               \
      unpk8(rb, u0, u1, u2, u3, u4, u5, u6, u7);                               \
      float vA = fma8(w0, w1, w2, w3, w4, w5, w6, w7,                          \
                      faA0, faA1, faA2, faA3, faA4, faA5, faA6, faA7, 0.f);    \
      pA##J = fma8(u0, u1, u2, u3, u4, u5, u6, u7,                             \
                   fbA0, fbA1, fbA2, fbA3, fbA4, fbA5, fbA6, fbA7, vA);        \
      float vB = fma8(w0, w1, w2, w3, w4, w5, w6, w7,                          \
                      faB0, faB1, faB2, faB3, faB4, faB5, faB6, faB7, 0.f);    \
      pB##J = fma8(u0, u1, u2, u3, u4, u5, u6, u7,                             \
                   fbB0, fbB1, fbB2, fbB3, fbB4, fbB5, fbB6, fbB7, vB);        \
      __builtin_amdgcn_sched_barrier(0);                                      \
    }
    REP16(K0J)
#undef K0J
    // packed butterfly, all named scalars; validated logic (kanE passed)
#define PAIR(KP, SA, SB, MASK)                                                 \
    ((KP) + __shfl_xor((SA) ? (SB) : (KP), (MASK), 64))
#define BFLY(p0_, p1_, p2_, p3_, p4_, p5_, p6_, p7_, p8_, p9_, p10_, p11_,     \
             p12_, p13_, p14_, p15_, OUTV)                                     \
    {                                                                          \
      float q0 = (b1 ? p1_ : p0_) + __shfl_xor(b1 ? p0_ : p1_, 1, 64);         \
      float q1 = (b1 ? p3_ : p2_) + __shfl_xor(b1 ? p2_ : p3_, 1, 64);         \
      float q2 = (b1 ? p5_ : p4_) + __shfl_xor(b1 ? p4_ : p5_, 1, 64);         \
      float q3 = (b1 ? p7_ : p6_) + __shfl_xor(b1 ? p6_ : p7_, 1, 64);         \
      float q4 = (b1 ? p9_ : p8_) + __shfl_xor(b1 ? p8_ : p9_, 1, 64);         \
      float q5 = (b1 ? p11_ : p10_) + __shfl_xor(b1 ? p10_ : p11_, 1, 64);     \
      float q6 = (b1 ? p13_ : p12_) + __shfl_xor(b1 ? p12_ : p13_, 1, 64);     \
      float q7 = (b1 ? p15_ : p14_) + __shfl_xor(b1 ? p14_ : p15_, 1, 64);     \
      float r0 = (b2 ? q1 : q0) + __shfl_xor(b2 ? q0 : q1, 2, 64);             \
      float r1 = (b2 ? q3 : q2) + __shfl_xor(b2 ? q2 : q3, 2, 64);             \
      float r2 = (b2 ? q5 : q4) + __shfl_xor(b2 ? q4 : q5, 2, 64);             \
      float r3 = (b2 ? q7 : q6) + __shfl_xor(b2 ? q6 : q7, 2, 64);             \
      float s0 = (b4 ? r1 : r0) + __shfl_xor(b4 ? r0 : r1, 4, 64);             \
      float s1 = (b4 ? r3 : r2) + __shfl_xor(b4 ? r2 : r3, 4, 64);             \
      float t_ = (b8 ? s1 : s0) + __shfl_xor(b8 ? s0 : s1, 8, 64);             \
      t_ += __shfl_xor(t_, 16, 64);                                            \
      t_ += __shfl_xor(t_, 32, 64);                                            \
      OUTV = t_;                                                               \
    }
    float hA, hB;
    BFLY(pA0, pA1, pA2, pA3, pA4, pA5, pA6, pA7, pA8, pA9, pA10, pA11, pA12,
         pA13, pA14, pA15, hA)
    BFLY(pB0, pB1, pB2, pB3, pB4, pB5, pB6, pB7, pB8, pB9, pB10, pB11, pB12,
         pB13, pB14, pB15, hB)
#undef BFLY
#undef PAIR
    if (o < 16) {
      hid[nodeA * 16 + o] = hA;
      hid[nodeB * 16 + o] = hB;
    }
  }
}

// ---------- kan1: hid -> out. 2 nodes/wave, shared unpack ----------
__global__ __launch_bounds__(512) void kan1(
    const float* __restrict__ hid, const u16* __restrict__ p1bf,
    float* __restrict__ out) {
  __shared__ u32 P1s[8192];   // 32 KB: uint4 record J*128 + o (transposed)
  const int tid = threadIdx.x;
  {
    const uint4* g1 = (const uint4*)p1bf;  // record r = o*16 + j
    uint4* s1 = (uint4*)P1s;
    for (int r = tid; r < 2048; r += 512) {
      int oo = r >> 4, j = r & 15;
      s1[j * 128 + oo] = g1[r];
    }
  }
  __syncthreads();
  const int o = tid & 63;
  const int wave = tid >> 6;
  const int j16 = o & 15;
  for (int pr = blockIdx.x * 8 + wave; pr < NN / 2; pr += 4096) {
    const int nodeA = pr * 2, nodeB = nodeA + 1;
    float hA = hid[nodeA * 16 + j16];
    float hB = hid[nodeB * 16 + j16];
    float fhA0, fhA1, fhA2, fhA3, fhA4, fhA5, fhA6, fhA7;
    float fhB0, fhB1, fhB2, fhB3, fhB4, fhB5, fhB6, fhB7;
    feat8s(hA, fhA0, fhA1, fhA2, fhA3, fhA4, fhA5, fhA6, fhA7);
    feat8s(hB, fhB0, fhB1, fhB2, fhB3, fhB4, fhB5, fhB6, fhB7);
    float accLoA = 0.f, accHiA = 0.f, accLoB = 0.f, accHiB = 0.f;
#define K1J(J)                                                                 \
    {                                                                          \
      uint4 ra = *(const uint4*)&P1s[(J) * 512 + o * 4];                       \
      uint4 rb = *(const uint4*)&P1s[(J) * 512 + (o + 64) * 4];                \
      float w0, w1, w2, w3, w4, w5, w6, w7, u0, u1, u2, u3, u4, u5, u6, u7;    \
      unpk8(ra, w0, w1, w2, w3, w4, w5, w6, w7);                               \
      unpk8(rb, u0, u1, u2, u3, u4, u5, u6, u7);                               \
      float qA0 = RL(fhA0, J), qA1 = RL(fhA1, J), qA2 = RL(fhA2, J),           \
            qA3 = RL(fhA3, J), qA4 = RL(fhA4, J), qA5 = RL(fhA5, J),           \
            qA6 = RL(fhA6, J), qA7 = RL(fhA7, J);                              \
      float qB0 = RL(fhB0, J), qB1 = RL(fhB1, J), qB2 = RL(fhB2, J),           \
            qB3 = RL(fhB3, J), qB4 = RL(fhB4, J), qB5 = RL(fhB5, J),           \
            qB6 = RL(fhB6, J), qB7 = RL(fhB7, J);                              \
      accLoA = fma8(w0, w1, w2, w3, w4, w5, w6, w7,                            \
                    qA0, qA1, qA2, qA3, qA4, qA5, qA6, qA7, accLoA);           \
      accHiA = fma8(u0, u1, u2, u3, u4, u5, u6, u7,                            \
                    qA0, qA1, qA2, qA3, qA4, qA5, qA6, qA7, accHiA);           \
      accLoB = fma8(w0, w1, w2, w3, w4, w5, w6, w7,                            \
                    qB0, qB1, qB2, qB3, qB4, qB5, qB6, qB7, accLoB);           \
      accHiB = fma8(u0, u1, u2, u3, u4, u5, u6, u7,                            \
                    qB0, qB1, qB2, qB3, qB4, qB5, qB6, qB7, accHiB);           \
      __builtin_amdgcn_sched_barrier(0);                                      \
    }
    REP16(K1J)
#undef K1J
    out[(size_t)nodeA * C + o] = accLoA;
    out[(size_t)nodeA * C + o + 64] = accHiA;
    out[(size_t)nodeB * C + o] = accLoB;
    out[(size_t)nodeB * C + o + 64] = accHiB;
  }
}

extern "C" void kernel_launch(void* const* d_in, const int* in_sizes, int n_in,
                              void* d_out, int out_size, void* d_ws, size_t ws_size,
                              hipStream_t stream) {
  const float* x   = (const float*)d_in[0];
  const int*   ei  = (const int*)d_in[1];
  const float* gw  = (const float*)d_in[2];
  const float* gb  = (const float*)d_in[3];
  const float* bw0 = (const float*)d_in[4];
  const float* sw0 = (const float*)d_in[5];
  const float* sc0 = (const float*)d_in[6];
  const float* bw1 = (const float*)d_in[7];
  const float* sw1 = (const float*)d_in[8];
  const float* sc1 = (const float*)d_in[9];
  float* out = (float*)d_out;

  char* p = (char*)d_ws;
  float* Wt = (float*)p;      p += C * C * 4;
  u16* p0bf = (u16*)p;        p += H * C * 8 * 2;
  u16* p1bf = (u16*)p;        p += C * H * 8 * 2;
  float* dinv = (float*)p;    p += NN * 4;
  int* cnt = (int*)p;         p += NN * 4;       // cnt+fillcnt adjacent:
  int* fillcnt = (int*)p;     p += NN * 4;       // one memset covers both
  int* excl = (int*)p;        p += NN * 4;
  int* bsums = (int*)p;       p += 256 * 4;
  int* row_start = (int*)p;   p += (NN + 4) * 4;
  float* hid = (float*)p;     p += (size_t)NN * H * 4;   // 3.2 MB
  int* csr = (int*)p;         p += (size_t)NE * 4;
  float* csrw = (float*)p;    p += (size_t)NE * 4;
  float* axh = (float*)p;     p += (size_t)NN * C * 4;

  const int* src = ei;
  const int* dst = ei + NE;

  hipMemsetAsync(cnt, 0, 2 * NN * 4, stream);

  prep_kernel<<<64, 256, 0, stream>>>(gw, bw0, sw0, sc0, bw1, sw1, sc1, Wt, p0bf, p1bf);
  count_kernel<<<(NE + 255) / 256, 256, 0, stream>>>(dst, cnt);
  scan1<<<196, 256, 0, stream>>>(cnt, excl, bsums, NN);
  scan2<<<1, 256, 0, stream>>>(bsums, 196);
  scan3<<<196, 256, 0, stream>>>(excl, bsums, cnt, row_start, dinv, NN);
  fill_kernel<<<(NE + 255) / 256, 256, 0, stream>>>(src, dst, row_start, dinv, fillcnt, csr, csrw);
  agg_kernel<<<NN / 2, 256, 0, stream>>>(x, csr, csrw, row_start, dinv, axh);
  gemm128<<<(NN + 63) / 64, 256, 0, stream>>>(Wt, axh);
  kan0<<<512, 512, 0, stream>>>(axh, gb, p0bf, hid);
  kan1<<<512, 512, 0, stream>>>(hid, p1bf, out);
}

// Round 11
// 288.141 us; speedup vs baseline: 2.9289x; 1.0834x over previous
//
#include <hip/hip_runtime.h>

#define NN 50000
#define NE 800000
#define C 128
#define H 16

typedef unsigned int u32;
typedef unsigned short u16;

// ---------- silu + 7 cubic B-spline bases, closed form, NAMED outputs ----------
__device__ __forceinline__ void feat8s(float x, float& s, float& g0, float& g1,
                                       float& g2, float& g3, float& g4, float& g5,
                                       float& g6) {
  s = x / (1.f + __expf(-x));
  float t = (x + 2.5f) * 2.0f;
  float cf = floorf(t);
  int c = (int)cf;
  float u = t - cf;
  float u2 = u * u, u3 = u2 * u;
  const float k6 = 1.f / 6.f;
  float P0 = u3 * k6;
  float P1 = (1.f + 3.f * u + 3.f * u2 - 3.f * u3) * k6;
  float P2 = (4.f - 6.f * u2 + 3.f * u3) * k6;
  float om = 1.f - u;
  float P3 = om * om * om * k6;
  bool valid = (t >= 0.f) && (t < 10.f);
#define SPJ(G, J)                                   \
  {                                                 \
    float b = 0.f;                                  \
    b = (c == (J)) ? P0 : b;                        \
    b = (c == (J) + 1) ? P1 : b;                    \
    b = (c == (J) + 2) ? P2 : b;                    \
    b = (c == (J) + 3) ? P3 : b;                    \
    G = valid ? b : 0.f;                            \
  }
  SPJ(g0, 0) SPJ(g1, 1) SPJ(g2, 2) SPJ(g3, 3) SPJ(g4, 4) SPJ(g5, 5) SPJ(g6, 6)
#undef SPJ
}

__device__ __forceinline__ u16 f2bf(float v) {
  u32 b = __float_as_uint(v);
  return (u16)((b + 0x7fffu + ((b >> 16) & 1u)) >> 16);  // RNE
}

__device__ __forceinline__ float blo(u32 v) { return __uint_as_float(v << 16); }
__device__ __forceinline__ float bhi(u32 v) { return __uint_as_float(v & 0xffff0000u); }

// unpack 8 bf16 (uint4) -> 8 named f32
__device__ __forceinline__ void unpk8(uint4 r, float& w0, float& w1, float& w2,
                                      float& w3, float& w4, float& w5, float& w6,
                                      float& w7) {
  w0 = blo(r.x); w1 = bhi(r.x);
  w2 = blo(r.y); w3 = bhi(r.y);
  w4 = blo(r.z); w5 = bhi(r.z);
  w6 = blo(r.w); w7 = bhi(r.w);
}

__device__ __forceinline__ float fma8(float w0, float w1, float w2, float w3,
                                      float w4, float w5, float w6, float w7,
                                      float a0, float a1, float a2, float a3,
                                      float a4, float a5, float a6, float a7,
                                      float acc) {
  acc = fmaf(w0, a0, acc); acc = fmaf(w1, a1, acc);
  acc = fmaf(w2, a2, acc); acc = fmaf(w3, a3, acc);
  acc = fmaf(w4, a4, acc); acc = fmaf(w5, a5, acc);
  acc = fmaf(w6, a6, acc); acc = fmaf(w7, a7, acc);
  return acc;
}

#define RL(x, J) __int_as_float(__builtin_amdgcn_readlane(__float_as_int(x), (J)))
#define REP16(M) M(0) M(1) M(2) M(3) M(4) M(5) M(6) M(7) M(8) M(9) M(10) M(11) M(12) M(13) M(14) M(15)

// ---------- prep: Wt transpose, bf16 KAN weights, bf16 copy of x ----------
__global__ void prep_kernel(const float* __restrict__ W,
                            const float* __restrict__ bw0, const float* __restrict__ sw0,
                            const float* __restrict__ sc0,
                            const float* __restrict__ bw1, const float* __restrict__ sw1,
                            const float* __restrict__ sc1,
                            const float* __restrict__ x,
                            float* __restrict__ Wt, u16* __restrict__ p0bf,
                            u16* __restrict__ p1bf, u32* __restrict__ xbf) {
  int i = blockIdx.x * blockDim.x + threadIdx.x;
  if (i < C * C) {
    int k = i >> 7, o = i & 127;
    Wt[k * C + o] = W[o * C + k];
  }
  if (i < H * C * 8) {
    int of = i >> 3, j = i & 7;
    float v = (j == 0) ? bw0[of] : sw0[of * 7 + (j - 1)] * sc0[of];
    p0bf[i] = f2bf(v);
  }
  if (i < C * H * 8) {
    int of = i >> 3, j = i & 7;
    float v = (j == 0) ? bw1[of] : sw1[of * 7 + (j - 1)] * sc1[of];
    p1bf[i] = f2bf(v);
  }
  if (i < NN * C / 4) {  // 4 floats -> 2 packed u32
    float4 v = *(const float4*)&x[(size_t)i * 4];
    u32 lo = (u32)f2bf(v.x) | ((u32)f2bf(v.y) << 16);
    u32 hi = (u32)f2bf(v.z) | ((u32)f2bf(v.w) << 16);
    *(uint2*)&xbf[(size_t)i * 2] = make_uint2(lo, hi);
  }
}

// ---------- in-degree count ----------
__global__ void count_kernel(const int* __restrict__ dst, int* __restrict__ cnt) {
  int e = blockIdx.x * blockDim.x + threadIdx.x;
  if (e < NE) atomicAdd(&cnt[dst[e]], 1);
}

// ---------- scan1: block-local exclusive scan + block totals ----------
__global__ void scan1(const int* __restrict__ cnt, int* __restrict__ excl,
                      int* __restrict__ bsums, int n) {
  int i = blockIdx.x * 256 + threadIdx.x;
  int v = (i < n) ? cnt[i] : 0;
  int lane = threadIdx.x & 63, wid = threadIdx.x >> 6;
  int s = v;
#pragma unroll
  for (int o = 1; o < 64; o <<= 1) {
    int t = __shfl_up(s, o, 64);
    if (lane >= o) s += t;
  }
  __shared__ int wsum[4];
  if (lane == 63) wsum[wid] = s;
  __syncthreads();
  int woff = 0;
  for (int w = 0; w < wid; ++w) woff += wsum[w];
  if (i < n) excl[i] = woff + s - v;
  if (threadIdx.x == 255) bsums[blockIdx.x] = woff + s;
}

// ---------- scan3 (scan2 folded in): per-block reduce of preceding bsums ----------
__global__ void scan3(const int* __restrict__ excl, const int* __restrict__ bsums,
                      const int* __restrict__ cnt, int* __restrict__ row_start,
                      float* __restrict__ dinv, int n, int nb) {
  __shared__ int red[256];
  const int t = threadIdx.x;
  red[t] = (t < nb && t < (int)blockIdx.x) ? bsums[t] : 0;
  __syncthreads();
#pragma unroll
  for (int s = 128; s > 0; s >>= 1) {
    if (t < s) red[t] += red[t + s];
    __syncthreads();
  }
  const int boff = red[0];
  const int i = blockIdx.x * 256 + t;
  if (i < n) {
    row_start[i] = excl[i] + boff;
    dinv[i] = rsqrtf((float)(cnt[i] + 1));
  }
  if (blockIdx.x == 0 && t == 0) row_start[n] = NE;
}

// ---------- CSR fill; csrw = dinv[src]*dinv[dst] ----------
__global__ void fill_kernel(const int* __restrict__ src, const int* __restrict__ dst,
                            const int* __restrict__ row_start, const float* __restrict__ dinv,
                            int* __restrict__ fillcnt, int* __restrict__ csr,
                            float* __restrict__ csrw) {
  int e = blockIdx.x * blockDim.x + threadIdx.x;
  if (e < NE) {
    int d = dst[e];
    int s = src[e];
    int p = atomicAdd(&fillcnt[d], 1);
    int slot = row_start[d] + p;
    csr[slot] = s;
    csrw[slot] = dinv[s] * dinv[d];
  }
}

// ---------- aggregation v2: bf16 x, 1 node/wave, unroll x8 ----------
// r10 profile: warm replays (x L3-resident, 26 MB fetch) ran SAME 72 us as
// cold -> latency-bound, not BW. Fixes: halve footprint (bf16, better L2
// residency), 8 gathers in flight, one wave per node (more node-parallelism).
__global__ __launch_bounds__(256, 8) void agg_kernel(
    const u32* __restrict__ xbf, const int* __restrict__ csr,
    const float* __restrict__ csrw, const int* __restrict__ row_start,
    const float* __restrict__ dinv, float* __restrict__ ax) {
  const int l = threadIdx.x & 63;          // lane covers channels 2l, 2l+1
  const int node = blockIdx.x * 4 + (threadIdx.x >> 6);
  const int e0 = row_start[node], e1 = row_start[node + 1];
  const float dn = dinv[node];
  const u32 vs = xbf[(size_t)node * 64 + l];
  float a0 = blo(vs) * (dn * dn);
  float a1 = bhi(vs) * (dn * dn);
  int e = e0;
  for (; e + 8 <= e1; e += 8) {
    const int s0 = csr[e], s1 = csr[e + 1], s2 = csr[e + 2], s3 = csr[e + 3];
    const int s4 = csr[e + 4], s5 = csr[e + 5], s6 = csr[e + 6], s7 = csr[e + 7];
    const float w0 = csrw[e], w1 = csrw[e + 1], w2 = csrw[e + 2], w3 = csrw[e + 3];
    const float w4 = csrw[e + 4], w5 = csrw[e + 5], w6 = csrw[e + 6], w7 = csrw[e + 7];
    const u32 v0 = xbf[(size_t)s0 * 64 + l];
    const u32 v1 = xbf[(size_t)s1 * 64 + l];
    const u32 v2 = xbf[(size_t)s2 * 64 + l];
    const u32 v3 = xbf[(size_t)s3 * 64 + l];
    const u32 v4 = xbf[(size_t)s4 * 64 + l];
    const u32 v5 = xbf[(size_t)s5 * 64 + l];
    const u32 v6 = xbf[(size_t)s6 * 64 + l];
    const u32 v7 = xbf[(size_t)s7 * 64 + l];
    a0 = fmaf(blo(v0), w0, a0); a1 = fmaf(bhi(v0), w0, a1);
    a0 = fmaf(blo(v1), w1, a0); a1 = fmaf(bhi(v1), w1, a1);
    a0 = fmaf(blo(v2), w2, a0); a1 = fmaf(bhi(v2), w2, a1);
    a0 = fmaf(blo(v3), w3, a0); a1 = fmaf(bhi(v3), w3, a1);
    a0 = fmaf(blo(v4), w4, a0); a1 = fmaf(bhi(v4), w4, a1);
    a0 = fmaf(blo(v5), w5, a0); a1 = fmaf(bhi(v5), w5, a1);
    a0 = fmaf(blo(v6), w6, a0); a1 = fmaf(bhi(v6), w6, a1);
    a0 = fmaf(blo(v7), w7, a0); a1 = fmaf(bhi(v7), w7, a1);
  }
  for (; e < e1; ++e) {
    const int s = csr[e];
    const float w = csrw[e];
    const u32 v = xbf[(size_t)s * 64 + l];
    a0 = fmaf(blo(v), w, a0);
    a1 = fmaf(bhi(v), w, a1);
  }
  *(float2*)&ax[(size_t)node * C + 2 * l] = make_float2(a0, a1);
}

// ---------- GEMV as tiled GEMM, in-place: h = ax @ W^T ----------
__global__ __launch_bounds__(256) void gemm128(const float* __restrict__ Wt,
                                               float* __restrict__ axh) {
  __shared__ float Xs[64][129];
  __shared__ float Ws[32][132];
  const int tid = threadIdx.x;
  const int n0 = blockIdx.x * 64;
#pragma unroll
  for (int it = 0; it < 8; ++it) {
    int idx = it * 1024 + tid * 4;
    int n = idx >> 7, k = idx & 127;
    float4 v = make_float4(0.f, 0.f, 0.f, 0.f);
    if (n0 + n < NN) v = *(const float4*)&axh[(size_t)(n0 + n) * C + k];
    *(float4*)&Xs[n][k] = v;
  }
  const int nt = tid & 15, ot = tid >> 4;
  float4 accA[4], accB[4];
#pragma unroll
  for (int d = 0; d < 4; ++d) {
    accA[d] = make_float4(0.f, 0.f, 0.f, 0.f);
    accB[d] = make_float4(0.f, 0.f, 0.f, 0.f);
  }
  for (int k0 = 0; k0 < 128; k0 += 32) {
    __syncthreads();
#pragma unroll
    for (int it = 0; it < 4; ++it) {
      int idx = it * 1024 + tid * 4;
      int k = idx >> 7, oo = idx & 127;
      *(float4*)&Ws[k][oo] = *(const float4*)&Wt[(k0 + k) * C + oo];
    }
    __syncthreads();
#pragma unroll
    for (int k = 0; k < 32; ++k) {
      float4 w0 = *(const float4*)&Ws[k][ot * 8];
      float4 w1 = *(const float4*)&Ws[k][ot * 8 + 4];
#pragma unroll
      for (int d = 0; d < 4; ++d) {
        float xv = Xs[nt * 4 + d][k0 + k];
        accA[d].x += xv * w0.x; accA[d].y += xv * w0.y;
        accA[d].z += xv * w0.z; accA[d].w += xv * w0.w;
        accB[d].x += xv * w1.x; accB[d].y += xv * w1.y;
        accB[d].z += xv * w1.z; accB[d].w += xv * w1.w;
      }
    }
  }
#pragma unroll
  for (int d = 0; d < 4; ++d) {
    int node = n0 + nt * 4 + d;
    if (node < NN) {
      *(float4*)&axh[(size_t)node * C + ot * 8] = accA[d];
      *(float4*)&axh[(size_t)node * C + ot * 8 + 4] = accB[d];
    }
  }
}

// ---------- kan0: h -> hid[NN][16]. 2 nodes/wave, shared unpack, packed BFLY ----------
__global__ __launch_bounds__(512) void kan0(
    const float* __restrict__ h, const float* __restrict__ bias,
    const u16* __restrict__ p0bf, float* __restrict__ hid) {
  __shared__ u32 P0s[8192];   // 32 KB: uint4 record J*128 + f
  const int tid = threadIdx.x;
  {
    const uint4* g0 = (const uint4*)p0bf;
    uint4* s0 = (uint4*)P0s;
    for (int r = tid; r < 2048; r += 512) s0[r] = g0[r];
  }
  __syncthreads();
  const int o = tid & 63;
  const int wave = tid >> 6;
  const float bLo = bias[o], bHi = bias[o + 64];
  const bool b1 = (o & 1), b2 = (o & 2), b4 = (o & 4), b8 = (o & 8);
  for (int pr = blockIdx.x * 8 + wave; pr < NN / 2; pr += 4096) {
    const int nodeA = pr * 2, nodeB = nodeA + 1;
    float faA0, faA1, faA2, faA3, faA4, faA5, faA6, faA7;
    float fbA0, fbA1, fbA2, fbA3, fbA4, fbA5, fbA6, fbA7;
    float faB0, faB1, faB2, faB3, faB4, faB5, faB6, faB7;
    float fbB0, fbB1, fbB2, fbB3, fbB4, fbB5, fbB6, fbB7;
    feat8s(h[(size_t)nodeA * C + o] + bLo, faA0, faA1, faA2, faA3, faA4, faA5, faA6, faA7);
    feat8s(h[(size_t)nodeA * C + o + 64] + bHi, fbA0, fbA1, fbA2, fbA3, fbA4, fbA5, fbA6, fbA7);
    feat8s(h[(size_t)nodeB * C + o] + bLo, faB0, faB1, faB2, faB3, faB4, faB5, faB6, faB7);
    feat8s(h[(size_t)nodeB * C + o + 64] + bHi, fbB0, fbB1, fbB2, fbB3, fbB4, fbB5, fbB6, fbB7);
#define K0J(J)                                                                 \
    float pA##J, pB##J;                                                        \
    {                                                                          \
      uint4 ra = *(const uint4*)&P0s[(J) * 512 + o * 4];                       \
      uint4 rb = *(const uint4*)&P0s[(J) * 512 + (o + 64) * 4];                \
      float w0, w1, w2, w3, w4, w5, w6, w7, u0, u1, u2, u3, u4, u5, u6, u7;    \
      unpk8(ra, w0, w1, w2, w3, w4, w5, w6, w7);                               \
      unpk8(rb, u0, u1, u2, u3, u4, u5, u6, u7);                               \
      float vA = fma8(w0, w1, w2, w3, w4, w5, w6, w7,                          \
                      faA0, faA1, faA2, faA3, faA4, faA5, faA6, faA7, 0.f);    \
      pA##J = fma8(u0, u1, u2, u3, u4, u5, u6, u7,                             \
                   fbA0, fbA1, fbA2, fbA3, fbA4, fbA5, fbA6, fbA7, vA);        \
      float vB = fma8(w0, w1, w2, w3, w4, w5, w6, w7,                          \
                      faB0, faB1, faB2, faB3, faB4, faB5, faB6, faB7, 0.f);    \
      pB##J = fma8(u0, u1, u2, u3, u4, u5, u6, u7,                             \
                   fbB0, fbB1, fbB2, fbB3, fbB4, fbB5, fbB6, fbB7, vB);        \
      __builtin_amdgcn_sched_barrier(0);                                      \
    }
    REP16(K0J)
#undef K0J
#define BFLY(p0_, p1_, p2_, p3_, p4_, p5_, p6_, p7_, p8_, p9_, p10_, p11_,     \
             p12_, p13_, p14_, p15_, OUTV)                                     \
    {                                                                          \
      float q0 = (b1 ? p1_ : p0_) + __shfl_xor(b1 ? p0_ : p1_, 1, 64);         \
      float q1 = (b1 ? p3_ : p2_) + __shfl_xor(b1 ? p2_ : p3_, 1, 64);         \
      float q2 = (b1 ? p5_ : p4_) + __shfl_xor(b1 ? p4_ : p5_, 1, 64);         \
      float q3 = (b1 ? p7_ : p6_) + __shfl_xor(b1 ? p6_ : p7_, 1, 64);         \
      float q4 = (b1 ? p9_ : p8_) + __shfl_xor(b1 ? p8_ : p9_, 1, 64);         \
      float q5 = (b1 ? p11_ : p10_) + __shfl_xor(b1 ? p10_ : p11_, 1, 64);     \
      float q6 = (b1 ? p13_ : p12_) + __shfl_xor(b1 ? p12_ : p13_, 1, 64);     \
      float q7 = (b1 ? p15_ : p14_) + __shfl_xor(b1 ? p14_ : p15_, 1, 64);     \
      float r0 = (b2 ? q1 : q0) + __shfl_xor(b2 ? q0 : q1, 2, 64);             \
      float r1 = (b2 ? q3 : q2) + __shfl_xor(b2 ? q2 : q3, 2, 64);             \
      float r2 = (b2 ? q5 : q4) + __shfl_xor(b2 ? q4 : q5, 2, 64);             \
      float r3 = (b2 ? q7 : q6) + __shfl_xor(b2 ? q6 : q7, 2, 64);             \
      float s0 = (b4 ? r1 : r0) + __shfl_xor(b4 ? r0 : r1, 4, 64);             \
      float s1 = (b4 ? r3 : r2) + __shfl_xor(b4 ? r2 : r3, 4, 64);             \
      float t_ = (b8 ? s1 : s0) + __shfl_xor(b8 ? s0 : s1, 8, 64);             \
      t_ += __shfl_xor(t_, 16, 64);                                            \
      t_ += __shfl_xor(t_, 32, 64);                                            \
      OUTV = t_;                                                               \
    }
    float hA, hB;
    BFLY(pA0, pA1, pA2, pA3, pA4, pA5, pA6, pA7, pA8, pA9, pA10, pA11, pA12,
         pA13, pA14, pA15, hA)
    BFLY(pB0, pB1, pB2, pB3, pB4, pB5, pB6, pB7, pB8, pB9, pB10, pB11, pB12,
         pB13, pB14, pB15, hB)
#undef BFLY
    if (o < 16) {
      hid[nodeA * 16 + o] = hA;
      hid[nodeB * 16 + o] = hB;
    }
  }
}

// ---------- kan1: hid -> out. 2 nodes/wave, shared unpack ----------
__global__ __launch_bounds__(512) void kan1(
    const float* __restrict__ hid, const u16* __restrict__ p1bf,
    float* __restrict__ out) {
  __shared__ u32 P1s[8192];   // 32 KB: uint4 record J*128 + o (transposed)
  const int tid = threadIdx.x;
  {
    const uint4* g1 = (const uint4*)p1bf;  // record r = o*16 + j
    uint4* s1 = (uint4*)P1s;
    for (int r = tid; r < 2048; r += 512) {
      int oo = r >> 4, j = r & 15;
      s1[j * 128 + oo] = g1[r];
    }
  }
  __syncthreads();
  const int o = tid & 63;
  const int wave = tid >> 6;
  const int j16 = o & 15;
  for (int pr = blockIdx.x * 8 + wave; pr < NN / 2; pr += 4096) {
    const int nodeA = pr * 2, nodeB = nodeA + 1;
    float hA = hid[nodeA * 16 + j16];
    float hB = hid[nodeB * 16 + j16];
    float fhA0, fhA1, fhA2, fhA3, fhA4, fhA5, fhA6, fhA7;
    float fhB0, fhB1, fhB2, fhB3, fhB4, fhB5, fhB6, fhB7;
    feat8s(hA, fhA0, fhA1, fhA2, fhA3, fhA4, fhA5, fhA6, fhA7);
    feat8s(hB, fhB0, fhB1, fhB2, fhB3, fhB4, fhB5, fhB6, fhB7);
    float accLoA = 0.f, accHiA = 0.f, accLoB = 0.f, accHiB = 0.f;
#define K1J(J)                                                                 \
    {                                                                          \
      uint4 ra = *(const uint4*)&P1s[(J) * 512 + o * 4];                       \
      uint4 rb = *(const uint4*)&P1s[(J) * 512 + (o + 64) * 4];                \
      float w0, w1, w2, w3, w4, w5, w6, w7, u0, u1, u2, u3, u4, u5, u6, u7;    \
      unpk8(ra, w0, w1, w2, w3, w4, w5, w6, w7);                               \
      unpk8(rb, u0, u1, u2, u3, u4, u5, u6, u7);                               \
      float qA0 = RL(fhA0, J), qA1 = RL(fhA1, J), qA2 = RL(fhA2, J),           \
            qA3 = RL(fhA3, J), qA4 = RL(fhA4, J), qA5 = RL(fhA5, J),           \
            qA6 = RL(fhA6, J), qA7 = RL(fhA7, J);                              \
      float qB0 = RL(fhB0, J), qB1 = RL(fhB1, J), qB2 = RL(fhB2, J),           \
            qB3 = RL(fhB3, J), qB4 = RL(fhB4, J), qB5 = RL(fhB5, J),           \
            qB6 = RL(fhB6, J), qB7 = RL(fhB7, J);                              \
      accLoA = fma8(w0, w1, w2, w3, w4, w5, w6, w7,                            \
                    qA0, qA1, qA2, qA3, qA4, qA5, qA6, qA7, accLoA);           \
      accHiA = fma8(u0, u1, u2, u3, u4, u5, u6, u7,                            \
                    qA0, qA1, qA2, qA3, qA4, qA5, qA6, qA7, accHiA);           \
      accLoB = fma8(w0, w1, w2, w3, w4, w5, w6, w7,                            \
                    qB0, qB1, qB2, qB3, qB4, qB5, qB6, qB7, accLoB);           \
      accHiB = fma8(u0, u1, u2, u3, u4, u5, u6, u7,                            \
                    qB0, qB1, qB2, qB3, qB4, qB5, qB6, qB7, accHiB);           \
      __builtin_amdgcn_sched_barrier(0);                                      \
    }
    REP16(K1J)
#undef K1J
    out[(size_t)nodeA * C + o] = accLoA;
    out[(size_t)nodeA * C + o + 64] = accHiA;
    out[(size_t)nodeB * C + o] = accLoB;
    out[(size_t)nodeB * C + o + 64] = accHiB;
  }
}

extern "C" void kernel_launch(void* const* d_in, const int* in_sizes, int n_in,
                              void* d_out, int out_size, void* d_ws, size_t ws_size,
                              hipStream_t stream) {
  const float* x   = (const float*)d_in[0];
  const int*   ei  = (const int*)d_in[1];
  const float* gw  = (const float*)d_in[2];
  const float* gb  = (const float*)d_in[3];
  const float* bw0 = (const float*)d_in[4];
  const float* sw0 = (const float*)d_in[5];
  const float* sc0 = (const float*)d_in[6];
  const float* bw1 = (const float*)d_in[7];
  const float* sw1 = (const float*)d_in[8];
  const float* sc1 = (const float*)d_in[9];
  float* out = (float*)d_out;

  char* p = (char*)d_ws;
  float* Wt = (float*)p;      p += C * C * 4;
  u16* p0bf = (u16*)p;        p += H * C * 8 * 2;
  u16* p1bf = (u16*)p;        p += C * H * 8 * 2;
  float* dinv = (float*)p;    p += NN * 4;
  int* cnt = (int*)p;         p += NN * 4;       // cnt+fillcnt adjacent:
  int* fillcnt = (int*)p;     p += NN * 4;       // one memset covers both
  int* excl = (int*)p;        p += NN * 4;
  int* bsums = (int*)p;       p += 256 * 4;
  int* row_start = (int*)p;   p += (NN + 4) * 4;
  float* hid = (float*)p;     p += (size_t)NN * H * 4;   // 3.2 MB
  u32* xbf = (u32*)p;         p += (size_t)NN * C * 2;   // 12.8 MB
  int* csr = (int*)p;         p += (size_t)NE * 4;
  float* csrw = (float*)p;    p += (size_t)NE * 4;
  float* axh = (float*)p;     p += (size_t)NN * C * 4;

  const int* src = ei;
  const int* dst = ei + NE;

  hipMemsetAsync(cnt, 0, 2 * NN * 4, stream);

  prep_kernel<<<6250, 256, 0, stream>>>(gw, bw0, sw0, sc0, bw1, sw1, sc1, x,
                                        Wt, p0bf, p1bf, xbf);
  count_kernel<<<(NE + 255) / 256, 256, 0, stream>>>(dst, cnt);
  scan1<<<196, 256, 0, stream>>>(cnt, excl, bsums, NN);
  scan3<<<196, 256, 0, stream>>>(excl, bsums, cnt, row_start, dinv, NN, 196);
  fill_kernel<<<(NE + 255) / 256, 256, 0, stream>>>(src, dst, row_start, dinv, fillcnt, csr, csrw);
  agg_kernel<<<NN / 4, 256, 0, stream>>>(xbf, csr, csrw, row_start, dinv, axh);
  gemm128<<<(NN + 63) / 64, 256, 0, stream>>>(Wt, axh);
  kan0<<<512, 512, 0, stream>>>(axh, gb, p0bf, hid);
  kan1<<<512, 512, 0, stream>>>(hid, p1bf, out);
}

// Round 13
// 249.627 us; speedup vs baseline: 3.3807x; 1.1543x over previous
//
#include <hip/hip_runtime.h>

#define NN 50000
#define NE 800000
#define C 128
#define H 16

typedef unsigned int u32;
typedef unsigned short u16;
typedef __fp16 h2 __attribute__((ext_vector_type(2)));

__device__ __forceinline__ h2 as_h2(u32 v) {
  union { u32 u; h2 h; } c; c.u = v; return c.h;
}
__device__ __forceinline__ u32 as_u32(h2 h) {
  union { u32 u; h2 h; } c; c.h = h; return c.u;
}
#define PK(a, b) __builtin_amdgcn_cvt_pkrtz((a), (b))
#define DOT2(w, f, acc) __builtin_amdgcn_fdot2((w), (f), (acc), false)

// ---------- silu + 7 cubic B-spline bases, closed form, NAMED outputs ----------
__device__ __forceinline__ void feat8s(float x, float& s, float& g0, float& g1,
                                       float& g2, float& g3, float& g4, float& g5,
                                       float& g6) {
  s = x / (1.f + __expf(-x));
  float t = (x + 2.5f) * 2.0f;
  float cf = floorf(t);
  int c = (int)cf;
  float u = t - cf;
  float u2 = u * u, u3 = u2 * u;
  const float k6 = 1.f / 6.f;
  float P0 = u3 * k6;
  float P1 = (1.f + 3.f * u + 3.f * u2 - 3.f * u3) * k6;
  float P2 = (4.f - 6.f * u2 + 3.f * u3) * k6;
  float om = 1.f - u;
  float P3 = om * om * om * k6;
  bool valid = (t >= 0.f) && (t < 10.f);
#define SPJ(G, J)                                   \
  {                                                 \
    float b = 0.f;                                  \
    b = (c == (J)) ? P0 : b;                        \
    b = (c == (J) + 1) ? P1 : b;                    \
    b = (c == (J) + 2) ? P2 : b;                    \
    b = (c == (J) + 3) ? P3 : b;                    \
    G = valid ? b : 0.f;                            \
  }
  SPJ(g0, 0) SPJ(g1, 1) SPJ(g2, 2) SPJ(g3, 3) SPJ(g4, 4) SPJ(g5, 5) SPJ(g6, 6)
#undef SPJ
}

__device__ __forceinline__ u16 f2bf(float v) {
  u32 b = __float_as_uint(v);
  return (u16)((b + 0x7fffu + ((b >> 16) & 1u)) >> 16);  // RNE
}
__device__ __forceinline__ u16 f2h(float v) {
  union { __fp16 h; u16 u; } c; c.h = (__fp16)v; return c.u;
}
__device__ __forceinline__ float blo(u32 v) { return __uint_as_float(v << 16); }
__device__ __forceinline__ float bhi(u32 v) { return __uint_as_float(v & 0xffff0000u); }

#define RLU(x, J) ((u32)__builtin_amdgcn_readlane((int)(x), (J)))
#define REP16(M) M(0) M(1) M(2) M(3) M(4) M(5) M(6) M(7) M(8) M(9) M(10) M(11) M(12) M(13) M(14) M(15)

// ---------- prep: Wt transpose, f16 KAN weights, bf16 copy of x ----------
__global__ void prep_kernel(const float* __restrict__ W,
                            const float* __restrict__ bw0, const float* __restrict__ sw0,
                            const float* __restrict__ sc0,
                            const float* __restrict__ bw1, const float* __restrict__ sw1,
                            const float* __restrict__ sc1,
                            const float* __restrict__ x,
                            float* __restrict__ Wt, u16* __restrict__ p0h,
                            u16* __restrict__ p1h, u32* __restrict__ xbf) {
  int i = blockIdx.x * blockDim.x + threadIdx.x;
  if (i < C * C) {
    int k = i >> 7, o = i & 127;
    Wt[k * C + o] = W[o * C + k];
  }
  if (i < H * C * 8) {
    int of = i >> 3, j = i & 7;
    float v = (j == 0) ? bw0[of] : sw0[of * 7 + (j - 1)] * sc0[of];
    p0h[i] = f2h(v);
  }
  if (i < C * H * 8) {
    int of = i >> 3, j = i & 7;
    float v = (j == 0) ? bw1[of] : sw1[of * 7 + (j - 1)] * sc1[of];
    p1h[i] = f2h(v);
  }
  if (i < NN * C / 4) {  // 4 floats -> 2 packed bf16 u32
    float4 v = *(const float4*)&x[(size_t)i * 4];
    u32 lo = (u32)f2bf(v.x) | ((u32)f2bf(v.y) << 16);
    u32 hi = (u32)f2bf(v.z) | ((u32)f2bf(v.w) << 16);
    *(uint2*)&xbf[(size_t)i * 2] = make_uint2(lo, hi);
  }
}

// ---------- in-degree count ----------
__global__ void count_kernel(const int* __restrict__ dst, int* __restrict__ cnt) {
  int e = blockIdx.x * blockDim.x + threadIdx.x;
  if (e < NE) atomicAdd(&cnt[dst[e]], 1);
}

// ---------- scan1: block-local exclusive scan + block totals ----------
__global__ void scan1(const int* __restrict__ cnt, int* __restrict__ excl,
                      int* __restrict__ bsums, int n) {
  int i = blockIdx.x * 256 + threadIdx.x;
  int v = (i < n) ? cnt[i] : 0;
  int lane = threadIdx.x & 63, wid = threadIdx.x >> 6;
  int s = v;
#pragma unroll
  for (int o = 1; o < 64; o <<= 1) {
    int t = __shfl_up(s, o, 64);
    if (lane >= o) s += t;
  }
  __shared__ int wsum[4];
  if (lane == 63) wsum[wid] = s;
  __syncthreads();
  int woff = 0;
  for (int w = 0; w < wid; ++w) woff += wsum[w];
  if (i < n) excl[i] = woff + s - v;
  if (threadIdx.x == 255) bsums[blockIdx.x] = woff + s;
}

// ---------- scan3 (scan2 folded in) ----------
__global__ void scan3(const int* __restrict__ excl, const int* __restrict__ bsums,
                      const int* __restrict__ cnt, int* __restrict__ row_start,
                      float* __restrict__ dinv, int n, int nb) {
  __shared__ int red[256];
  const int t = threadIdx.x;
  red[t] = (t < nb && t < (int)blockIdx.x) ? bsums[t] : 0;
  __syncthreads();
#pragma unroll
  for (int s = 128; s > 0; s >>= 1) {
    if (t < s) red[t] += red[t + s];
    __syncthreads();
  }
  const int boff = red[0];
  const int i = blockIdx.x * 256 + t;
  if (i < n) {
    row_start[i] = excl[i] + boff;
    dinv[i] = rsqrtf((float)(cnt[i] + 1));
  }
  if (blockIdx.x == 0 && t == 0) row_start[n] = NE;
}

// ---------- CSR fill ----------
__global__ void fill_kernel(const int* __restrict__ src, const int* __restrict__ dst,
                            const int* __restrict__ row_start, const float* __restrict__ dinv,
                            int* __restrict__ fillcnt, int* __restrict__ csr,
                            float* __restrict__ csrw) {
  int e = blockIdx.x * blockDim.x + threadIdx.x;
  if (e < NE) {
    int d = dst[e];
    int s = src[e];
    int p = atomicAdd(&fillcnt[d], 1);
    int slot = row_start[d] + p;
    csr[slot] = s;
    csrw[slot] = dinv[s] * dinv[d];
  }
}

// ---------- aggregation (r11 version, unchanged) ----------
__global__ __launch_bounds__(256, 8) void agg_kernel(
    const u32* __restrict__ xbf, const int* __restrict__ csr,
    const float* __restrict__ csrw, const int* __restrict__ row_start,
    const float* __restrict__ dinv, float* __restrict__ ax) {
  const int l = threadIdx.x & 63;
  const int node = blockIdx.x * 4 + (threadIdx.x >> 6);
  const int e0 = row_start[node], e1 = row_start[node + 1];
  const float dn = dinv[node];
  const u32 vs = xbf[(size_t)node * 64 + l];
  float a0 = blo(vs) * (dn * dn);
  float a1 = bhi(vs) * (dn * dn);
  int e = e0;
  for (; e + 8 <= e1; e += 8) {
    const int s0 = csr[e], s1 = csr[e + 1], s2 = csr[e + 2], s3 = csr[e + 3];
    const int s4 = csr[e + 4], s5 = csr[e + 5], s6 = csr[e + 6], s7 = csr[e + 7];
    const float w0 = csrw[e], w1 = csrw[e + 1], w2 = csrw[e + 2], w3 = csrw[e + 3];
    const float w4 = csrw[e + 4], w5 = csrw[e + 5], w6 = csrw[e + 6], w7 = csrw[e + 7];
    const u32 v0 = xbf[(size_t)s0 * 64 + l];
    const u32 v1 = xbf[(size_t)s1 * 64 + l];
    const u32 v2 = xbf[(size_t)s2 * 64 + l];
    const u32 v3 = xbf[(size_t)s3 * 64 + l];
    const u32 v4 = xbf[(size_t)s4 * 64 + l];
    const u32 v5 = xbf[(size_t)s5 * 64 + l];
    const u32 v6 = xbf[(size_t)s6 * 64 + l];
    const u32 v7 = xbf[(size_t)s7 * 64 + l];
    a0 = fmaf(blo(v0), w0, a0); a1 = fmaf(bhi(v0), w0, a1);
    a0 = fmaf(blo(v1), w1, a0); a1 = fmaf(bhi(v1), w1, a1);
    a0 = fmaf(blo(v2), w2, a0); a1 = fmaf(bhi(v2), w2, a1);
    a0 = fmaf(blo(v3), w3, a0); a1 = fmaf(bhi(v3), w3, a1);
    a0 = fmaf(blo(v4), w4, a0); a1 = fmaf(bhi(v4), w4, a1);
    a0 = fmaf(blo(v5), w5, a0); a1 = fmaf(bhi(v5), w5, a1);
    a0 = fmaf(blo(v6), w6, a0); a1 = fmaf(bhi(v6), w6, a1);
    a0 = fmaf(blo(v7), w7, a0); a1 = fmaf(bhi(v7), w7, a1);
  }
  for (; e < e1; ++e) {
    const int s = csr[e];
    const float w = csrw[e];
    const u32 v = xbf[(size_t)s * 64 + l];
    a0 = fmaf(blo(v), w, a0);
    a1 = fmaf(bhi(v), w, a1);
  }
  *(float2*)&ax[(size_t)node * C + 2 * l] = make_float2(a0, a1);
}

// ---------- GEMV as tiled GEMM, in-place (unchanged) ----------
__global__ __launch_bounds__(256) void gemm128(const float* __restrict__ Wt,
                                               float* __restrict__ axh) {
  __shared__ float Xs[64][129];
  __shared__ float Ws[32][132];
  const int tid = threadIdx.x;
  const int n0 = blockIdx.x * 64;
#pragma unroll
  for (int it = 0; it < 8; ++it) {
    int idx = it * 1024 + tid * 4;
    int n = idx >> 7, k = idx & 127;
    float4 v = make_float4(0.f, 0.f, 0.f, 0.f);
    if (n0 + n < NN) v = *(const float4*)&axh[(size_t)(n0 + n) * C + k];
    *(float4*)&Xs[n][k] = v;
  }
  const int nt = tid & 15, ot = tid >> 4;
  float4 accA[4], accB[4];
#pragma unroll
  for (int d = 0; d < 4; ++d) {
    accA[d] = make_float4(0.f, 0.f, 0.f, 0.f);
    accB[d] = make_float4(0.f, 0.f, 0.f, 0.f);
  }
  for (int k0 = 0; k0 < 128; k0 += 32) {
    __syncthreads();
#pragma unroll
    for (int it = 0; it < 4; ++it) {
      int idx = it * 1024 + tid * 4;
      int k = idx >> 7, oo = idx & 127;
      *(float4*)&Ws[k][oo] = *(const float4*)&Wt[(k0 + k) * C + oo];
    }
    __syncthreads();
#pragma unroll
    for (int k = 0; k < 32; ++k) {
      float4 w0 = *(const float4*)&Ws[k][ot * 8];
      float4 w1 = *(const float4*)&Ws[k][ot * 8 + 4];
#pragma unroll
      for (int d = 0; d < 4; ++d) {
        float xv = Xs[nt * 4 + d][k0 + k];
        accA[d].x += xv * w0.x; accA[d].y += xv * w0.y;
        accA[d].z += xv * w0.z; accA[d].w += xv * w0.w;
        accB[d].x += xv * w1.x; accB[d].y += xv * w1.y;
        accB[d].z += xv * w1.z; accB[d].w += xv * w1.w;
      }
    }
  }
#pragma unroll
  for (int d = 0; d < 4; ++d) {
    int node = n0 + nt * 4 + d;
    if (node < NN) {
      *(float4*)&axh[(size_t)node * C + ot * 8] = accA[d];
      *(float4*)&axh[(size_t)node * C + ot * 8 + 4] = accB[d];
    }
  }
}

// ---------- kan0f: h -> hid via v_dot2_f32_f16 (f16 weights, packed feats) ----------
__global__ __launch_bounds__(512) void kan0f(
    const float* __restrict__ h, const float* __restrict__ bias,
    const u16* __restrict__ p0h, float* __restrict__ hid) {
  __shared__ u32 P0s[8192];   // 32 KB: uint4 record J*128 + f  (8 f16 each)
  const int tid = threadIdx.x;
  {
    const uint4* g0 = (const uint4*)p0h;
    uint4* s0 = (uint4*)P0s;
    for (int r = tid; r < 2048; r += 512) s0[r] = g0[r];
  }
  __syncthreads();
  const int o = tid & 63;
  const int wave = tid >> 6;
  const float bLo = bias[o], bHi = bias[o + 64];
  const bool b1 = (o & 1), b2 = (o & 2), b4 = (o & 4), b8 = (o & 8);
  const int stride = gridDim.x * 8;
  for (int pr = blockIdx.x * 8 + wave; pr < NN / 2; pr += stride) {
    const int nodeA = pr * 2, nodeB = nodeA + 1;
    float t0, t1, t2, t3, t4, t5, t6, t7;
    feat8s(h[(size_t)nodeA * C + o] + bLo, t0, t1, t2, t3, t4, t5, t6, t7);
    h2 aA0 = PK(t0, t1), aA1 = PK(t2, t3), aA2 = PK(t4, t5), aA3 = PK(t6, t7);
    feat8s(h[(size_t)nodeA * C + o + 64] + bHi, t0, t1, t2, t3, t4, t5, t6, t7);
    h2 bA0 = PK(t0, t1), bA1 = PK(t2, t3), bA2 = PK(t4, t5), bA3 = PK(t6, t7);
    feat8s(h[(size_t)nodeB * C + o] + bLo, t0, t1, t2, t3, t4, t5, t6, t7);
    h2 aB0 = PK(t0, t1), aB1 = PK(t2, t3), aB2 = PK(t4, t5), aB3 = PK(t6, t7);
    feat8s(h[(size_t)nodeB * C + o + 64] + bHi, t0, t1, t2, t3, t4, t5, t6, t7);
    h2 bB0 = PK(t0, t1), bB1 = PK(t2, t3), bB2 = PK(t4, t5), bB3 = PK(t6, t7);
#define K0J(J)                                                                 \
    float pA##J, pB##J;                                                        \
    {                                                                          \
      uint4 ra = *(const uint4*)&P0s[(J) * 512 + o * 4];                       \
      uint4 rb = *(const uint4*)&P0s[(J) * 512 + (o + 64) * 4];                \
      float vA = DOT2(as_h2(ra.x), aA0, 0.f);                                  \
      vA = DOT2(as_h2(ra.y), aA1, vA);                                         \
      vA = DOT2(as_h2(ra.z), aA2, vA);                                         \
      vA = DOT2(as_h2(ra.w), aA3, vA);                                         \
      vA = DOT2(as_h2(rb.x), bA0, vA);                                         \
      vA = DOT2(as_h2(rb.y), bA1, vA);                                         \
      vA = DOT2(as_h2(rb.z), bA2, vA);                                         \
      pA##J = DOT2(as_h2(rb.w), bA3, vA);                                      \
      float vB = DOT2(as_h2(ra.x), aB0, 0.f);                                  \
      vB = DOT2(as_h2(ra.y), aB1, vB);                                         \
      vB = DOT2(as_h2(ra.z), aB2, vB);                                         \
      vB = DOT2(as_h2(ra.w), aB3, vB);                                         \
      vB = DOT2(as_h2(rb.x), bB0, vB);                                         \
      vB = DOT2(as_h2(rb.y), bB1, vB);                                         \
      vB = DOT2(as_h2(rb.z), bB2, vB);                                         \
      pB##J = DOT2(as_h2(rb.w), bB3, vB);                                      \
      __builtin_amdgcn_sched_barrier(0);                                      \
    }
    REP16(K0J)
#undef K0J
#define BFLY(p0_, p1_, p2_, p3_, p4_, p5_, p6_, p7_, p8_, p9_, p10_, p11_,     \
             p12_, p13_, p14_, p15_, OUTV)                                     \
    {                                                                          \
      float q0 = (b1 ? p1_ : p0_) + __shfl_xor(b1 ? p0_ : p1_, 1, 64);         \
      float q1 = (b1 ? p3_ : p2_) + __shfl_xor(b1 ? p2_ : p3_, 1, 64);         \
      float q2 = (b1 ? p5_ : p4_) + __shfl_xor(b1 ? p4_ : p5_, 1, 64);         \
      float q3 = (b1 ? p7_ : p6_) + __shfl_xor(b1 ? p6_ : p7_, 1, 64);         \
      float q4 = (b1 ? p9_ : p8_) + __shfl_xor(b1 ? p8_ : p9_, 1, 64);         \
      float q5 = (b1 ? p11_ : p10_) + __shfl_xor(b1 ? p10_ : p11_, 1, 64);     \
      float q6 = (b1 ? p13_ : p12_) + __shfl_xor(b1 ? p12_ : p13_, 1, 64);     \
      float q7 = (b1 ? p15_ : p14_) + __shfl_xor(b1 ? p14_ : p15_, 1, 64);     \
      float r0 = (b2 ? q1 : q0) + __shfl_xor(b2 ? q0 : q1, 2, 64);             \
      float r1 = (b2 ? q3 : q2) + __shfl_xor(b2 ? q2 : q3, 2, 64);             \
      float r2 = (b2 ? q5 : q4) + __shfl_xor(b2 ? q4 : q5, 2, 64);             \
      float r3 = (b2 ? q7 : q6) + __shfl_xor(b2 ? q6 : q7, 2, 64);             \
      float s0 = (b4 ? r1 : r0) + __shfl_xor(b4 ? r0 : r1, 4, 64);             \
      float s1 = (b4 ? r3 : r2) + __shfl_xor(b4 ? r2 : r3, 4, 64);             \
      float t_ = (b8 ? s1 : s0) + __shfl_xor(b8 ? s0 : s1, 8, 64);             \
      t_ += __shfl_xor(t_, 16, 64);                                            \
      t_ += __shfl_xor(t_, 32, 64);                                            \
      OUTV = t_;                                                               \
    }
    float hA, hB;
    BFLY(pA0, pA1, pA2, pA3, pA4, pA5, pA6, pA7, pA8, pA9, pA10, pA11, pA12,
         pA13, pA14, pA15, hA)
    BFLY(pB0, pB1, pB2, pB3, pB4, pB5, pB6, pB7, pB8, pB9, pB10, pB11, pB12,
         pB13, pB14, pB15, hB)
#undef BFLY
    if (o < 16) {
      hid[nodeA * 16 + o] = hA;
      hid[nodeB * 16 + o] = hB;
    }
  }
}

// ---------- kan1f: hid -> out via v_dot2_f32_f16 ----------
__global__ __launch_bounds__(512) void kan1f(
    const float* __restrict__ hid, const u16* __restrict__ p1h,
    float* __restrict__ out) {
  __shared__ u32 P1s[8192];   // 32 KB: uint4 record J*128 + o (transposed)
  const int tid = threadIdx.x;
  {
    const uint4* g1 = (const uint4*)p1h;  // record r = o*16 + j
    uint4* s1 = (uint4*)P1s;
    for (int r = tid; r < 2048; r += 512) {
      int oo = r >> 4, j = r & 15;
      s1[j * 128 + oo] = g1[r];
    }
  }
  __syncthreads();
  const int o = tid & 63;
  const int wave = tid >> 6;
  const int j16 = o & 15;
  const int stride = gridDim.x * 8;
  for (int pr = blockIdx.x * 8 + wave; pr < NN / 2; pr += stride) {
    const int nodeA = pr * 2, nodeB = nodeA + 1;
    float t0, t1, t2, t3, t4, t5, t6, t7;
    feat8s(hid[nodeA * 16 + j16], t0, t1, t2, t3, t4, t5, t6, t7);
    u32 uA0 = as_u32(PK(t0, t1)), uA1 = as_u32(PK(t2, t3));
    u32 uA2 = as_u32(PK(t4, t5)), uA3 = as_u32(PK(t6, t7));
    feat8s(hid[nodeB * 16 + j16], t0, t1, t2, t3, t4, t5, t6, t7);
    u32 uB0 = as_u32(PK(t0, t1)), uB1 = as_u32(PK(t2, t3));
    u32 uB2 = as_u32(PK(t4, t5)), uB3 = as_u32(PK(t6, t7));
    float accLoA = 0.f, accHiA = 0.f, accLoB = 0.f, accHiB = 0.f;
#define K1J(J)                                                                 \
    {                                                                          \
      uint4 ra = *(const uint4*)&P1s[(J) * 512 + o * 4];                       \
      uint4 rb = *(const uint4*)&P1s[(J) * 512 + (o + 64) * 4];                \
      h2 qA0 = as_h2(RLU(uA0, J)), qA1 = as_h2(RLU(uA1, J));                   \
      h2 qA2 = as_h2(RLU(uA2, J)), qA3 = as_h2(RLU(uA3, J));                   \
      h2 qB0 = as_h2(RLU(uB0, J)), qB1 = as_h2(RLU(uB1, J));                   \
      h2 qB2 = as_h2(RLU(uB2, J)), qB3 = as_h2(RLU(uB3, J));                   \
      accLoA = DOT2(as_h2(ra.x), qA0, accLoA);                                 \
      accLoA = DOT2(as_h2(ra.y), qA1, accLoA);                                 \
      accLoA = DOT2(as_h2(ra.z), qA2, accLoA);                                 \
      accLoA = DOT2(as_h2(ra.w), qA3, accLoA);                                 \
      accHiA = DOT2(as_h2(rb.x), qA0, accHiA);                                 \
      accHiA = DOT2(as_h2(rb.y), qA1, accHiA);                                 \
      accHiA = DOT2(as_h2(rb.z), qA2, accHiA);                                 \
      accHiA = DOT2(as_h2(rb.w), qA3, accHiA);                                 \
      accLoB = DOT2(as_h2(ra.x), qB0, accLoB);                                 \
      accLoB = DOT2(as_h2(ra.y), qB1, accLoB);                                 \
      accLoB = DOT2(as_h2(ra.z), qB2, accLoB);                                 \
      accLoB = DOT2(as_h2(ra.w), qB3, accLoB);                                 \
      accHiB = DOT2(as_h2(rb.x), qB0, accHiB);                                 \
      accHiB = DOT2(as_h2(rb.y), qB1, accHiB);                                 \
      accHiB = DOT2(as_h2(rb.z), qB2, accHiB);                                 \
      accHiB = DOT2(as_h2(rb.w), qB3, accHiB);                                 \
      __builtin_amdgcn_sched_barrier(0);                                      \
    }
    REP16(K1J)
#undef K1J
    out[(size_t)nodeA * C + o] = accLoA;
    out[(size_t)nodeA * C + o + 64] = accHiA;
    out[(size_t)nodeB * C + o] = accLoB;
    out[(size_t)nodeB * C + o + 64] = accHiB;
  }
}

extern "C" void kernel_launch(void* const* d_in, const int* in_sizes, int n_in,
                              void* d_out, int out_size, void* d_ws, size_t ws_size,
                              hipStream_t stream) {
  const float* x   = (const float*)d_in[0];
  const int*   ei  = (const int*)d_in[1];
  const float* gw  = (const float*)d_in[2];
  const float* gb  = (const float*)d_in[3];
  const float* bw0 = (const float*)d_in[4];
  const float* sw0 = (const float*)d_in[5];
  const float* sc0 = (const float*)d_in[6];
  const float* bw1 = (const float*)d_in[7];
  const float* sw1 = (const float*)d_in[8];
  const float* sc1 = (const float*)d_in[9];
  float* out = (float*)d_out;

  char* p = (char*)d_ws;
  float* Wt = (float*)p;      p += C * C * 4;
  u16* p0h = (u16*)p;         p += H * C * 8 * 2;
  u16* p1h = (u16*)p;         p += C * H * 8 * 2;
  float* dinv = (float*)p;    p += NN * 4;
  int* cnt = (int*)p;         p += NN * 4;       // cnt+fillcnt adjacent
  int* fillcnt = (int*)p;     p += NN * 4;
  int* excl = (int*)p;        p += NN * 4;
  int* bsums = (int*)p;       p += 256 * 4;
  int* row_start = (int*)p;   p += (NN + 4) * 4;
  float* hid = (float*)p;     p += (size_t)NN * H * 4;
  u32* xbf = (u32*)p;         p += (size_t)NN * C * 2;
  int* csr = (int*)p;         p += (size_t)NE * 4;
  float* csrw = (float*)p;    p += (size_t)NE * 4;
  float* axh = (float*)p;     p += (size_t)NN * C * 4;

  const int* src = ei;
  const int* dst = ei + NE;

  hipMemsetAsync(cnt, 0, 2 * NN * 4, stream);

  prep_kernel<<<6250, 256, 0, stream>>>(gw, bw0, sw0, sc0, bw1, sw1, sc1, x,
                                        Wt, p0h, p1h, xbf);
  count_kernel<<<(NE + 255) / 256, 256, 0, stream>>>(dst, cnt);
  scan1<<<196, 256, 0, stream>>>(cnt, excl, bsums, NN);
  scan3<<<196, 256, 0, stream>>>(excl, bsums, cnt, row_start, dinv, NN, 196);
  fill_kernel<<<(NE + 255) / 256, 256, 0, stream>>>(src, dst, row_start, dinv, fillcnt, csr, csrw);
  agg_kernel<<<NN / 4, 256, 0, stream>>>(xbf, csr, csrw, row_start, dinv, axh);
  gemm128<<<(NN + 63) / 64, 256, 0, stream>>>(Wt, axh);
  kan0f<<<1024, 512, 0, stream>>>(axh, gb, p0h, hid);
  kan1f<<<1024, 512, 0, stream>>>(hid, p1h, out);
}

// Round 14
// 231.220 us; speedup vs baseline: 3.6499x; 1.0796x over previous
//
#include <hip/hip_runtime.h>

#define NN 50000
#define NE 800000
#define C 128
#define H 16

typedef unsigned int u32;
typedef unsigned short u16;
typedef __fp16 h2 __attribute__((ext_vector_type(2)));
typedef __fp16 half8 __attribute__((ext_vector_type(8)));
typedef float f32x4 __attribute__((ext_vector_type(4)));

__device__ __forceinline__ h2 as_h2(u32 v) {
  union { u32 u; h2 h; } c; c.u = v; return c.h;
}
__device__ __forceinline__ u32 as_u32(h2 h) {
  union { u32 u; h2 h; } c; c.h = h; return c.u;
}
__device__ __forceinline__ half8 as_half8(uint4 v) {
  union { uint4 u; half8 h; } c; c.u = v; return c.h;
}
#define PK(a, b) __builtin_amdgcn_cvt_pkrtz((a), (b))
#define DOT2(w, f, acc) __builtin_amdgcn_fdot2((w), (f), (acc), false)

// ---------- silu + 7 cubic B-spline bases, closed form, NAMED outputs ----------
__device__ __forceinline__ void feat8s(float x, float& s, float& g0, float& g1,
                                       float& g2, float& g3, float& g4, float& g5,
                                       float& g6) {
  s = x / (1.f + __expf(-x));
  float t = (x + 2.5f) * 2.0f;
  float cf = floorf(t);
  int c = (int)cf;
  float u = t - cf;
  float u2 = u * u, u3 = u2 * u;
  const float k6 = 1.f / 6.f;
  float P0 = u3 * k6;
  float P1 = (1.f + 3.f * u + 3.f * u2 - 3.f * u3) * k6;
  float P2 = (4.f - 6.f * u2 + 3.f * u3) * k6;
  float om = 1.f - u;
  float P3 = om * om * om * k6;
  bool valid = (t >= 0.f) && (t < 10.f);
#define SPJ(G, J)                                   \
  {                                                 \
    float b = 0.f;                                  \
    b = (c == (J)) ? P0 : b;                        \
    b = (c == (J) + 1) ? P1 : b;                    \
    b = (c == (J) + 2) ? P2 : b;                    \
    b = (c == (J) + 3) ? P3 : b;                    \
    G = valid ? b : 0.f;                            \
  }
  SPJ(g0, 0) SPJ(g1, 1) SPJ(g2, 2) SPJ(g3, 3) SPJ(g4, 4) SPJ(g5, 5) SPJ(g6, 6)
#undef SPJ
}

__device__ __forceinline__ u16 f2bf(float v) {
  u32 b = __float_as_uint(v);
  return (u16)((b + 0x7fffu + ((b >> 16) & 1u)) >> 16);  // RNE
}
__device__ __forceinline__ u16 f2h(float v) {
  union { __fp16 h; u16 u; } c; c.h = (__fp16)v; return c.u;
}
__device__ __forceinline__ float blo(u32 v) { return __uint_as_float(v << 16); }
__device__ __forceinline__ float bhi(u32 v) { return __uint_as_float(v & 0xffff0000u); }

#define RLU(x, J) ((u32)__builtin_amdgcn_readlane((int)(x), (J)))
#define REP16(M) M(0) M(1) M(2) M(3) M(4) M(5) M(6) M(7) M(8) M(9) M(10) M(11) M(12) M(13) M(14) M(15)

// ---------- prep: f16 W, f16 KAN weights, bf16 copy of x ----------
__global__ void prep_kernel(const float* __restrict__ W,
                            const float* __restrict__ bw0, const float* __restrict__ sw0,
                            const float* __restrict__ sc0,
                            const float* __restrict__ bw1, const float* __restrict__ sw1,
                            const float* __restrict__ sc1,
                            const float* __restrict__ x,
                            u32* __restrict__ W16, u16* __restrict__ p0h,
                            u16* __restrict__ p1h, u32* __restrict__ xbf) {
  int i = blockIdx.x * blockDim.x + threadIdx.x;
  if (i < C * C / 2) {  // W row-major, packed f16 pairs along k
    int o = i >> 6, kp = i & 63;
    W16[i] = (u32)f2h(W[o * C + kp * 2]) | ((u32)f2h(W[o * C + kp * 2 + 1]) << 16);
  }
  if (i < H * C * 8) {
    int of = i >> 3, j = i & 7;
    float v = (j == 0) ? bw0[of] : sw0[of * 7 + (j - 1)] * sc0[of];
    p0h[i] = f2h(v);
  }
  if (i < C * H * 8) {
    int of = i >> 3, j = i & 7;
    float v = (j == 0) ? bw1[of] : sw1[of * 7 + (j - 1)] * sc1[of];
    p1h[i] = f2h(v);
  }
  if (i < NN * C / 4) {  // 4 floats -> 2 packed bf16 u32
    float4 v = *(const float4*)&x[(size_t)i * 4];
    u32 lo = (u32)f2bf(v.x) | ((u32)f2bf(v.y) << 16);
    u32 hi = (u32)f2bf(v.z) | ((u32)f2bf(v.w) << 16);
    *(uint2*)&xbf[(size_t)i * 2] = make_uint2(lo, hi);
  }
}

// ---------- in-degree count ----------
__global__ void count_kernel(const int* __restrict__ dst, int* __restrict__ cnt) {
  int e = blockIdx.x * blockDim.x + threadIdx.x;
  if (e < NE) atomicAdd(&cnt[dst[e]], 1);
}

// ---------- scan1: block-local exclusive scan + block totals ----------
__global__ void scan1(const int* __restrict__ cnt, int* __restrict__ excl,
                      int* __restrict__ bsums, int n) {
  int i = blockIdx.x * 256 + threadIdx.x;
  int v = (i < n) ? cnt[i] : 0;
  int lane = threadIdx.x & 63, wid = threadIdx.x >> 6;
  int s = v;
#pragma unroll
  for (int o = 1; o < 64; o <<= 1) {
    int t = __shfl_up(s, o, 64);
    if (lane >= o) s += t;
  }
  __shared__ int wsum[4];
  if (lane == 63) wsum[wid] = s;
  __syncthreads();
  int woff = 0;
  for (int w = 0; w < wid; ++w) woff += wsum[w];
  if (i < n) excl[i] = woff + s - v;
  if (threadIdx.x == 255) bsums[blockIdx.x] = woff + s;
}

// ---------- scan3 (scan2 folded in) ----------
__global__ void scan3(const int* __restrict__ excl, const int* __restrict__ bsums,
                      const int* __restrict__ cnt, int* __restrict__ row_start,
                      float* __restrict__ dinv, int n, int nb) {
  __shared__ int red[256];
  const int t = threadIdx.x;
  red[t] = (t < nb && t < (int)blockIdx.x) ? bsums[t] : 0;
  __syncthreads();
#pragma unroll
  for (int s = 128; s > 0; s >>= 1) {
    if (t < s) red[t] += red[t + s];
    __syncthreads();
  }
  const int boff = red[0];
  const int i = blockIdx.x * 256 + t;
  if (i < n) {
    row_start[i] = excl[i] + boff;
    dinv[i] = rsqrtf((float)(cnt[i] + 1));
  }
  if (blockIdx.x == 0 && t == 0) row_start[n] = NE;
}

// ---------- CSR fill: single 8B scatter per edge {src, w} ----------
__global__ void fill_kernel(const int* __restrict__ src, const int* __restrict__ dst,
                            const int* __restrict__ row_start, const float* __restrict__ dinv,
                            int* __restrict__ fillcnt, int2* __restrict__ edges) {
  int e = blockIdx.x * blockDim.x + threadIdx.x;
  if (e < NE) {
    int d = dst[e];
    int s = src[e];
    int p = atomicAdd(&fillcnt[d], 1);
    edges[row_start[d] + p] = make_int2(s, __float_as_int(dinv[s] * dinv[d]));
  }
}

// ---------- aggregation: bf16 x gathers, int2 edge stream, f16 out ----------
__global__ __launch_bounds__(256, 8) void agg_kernel(
    const u32* __restrict__ xbf, const int2* __restrict__ edges,
    const int* __restrict__ row_start, const float* __restrict__ dinv,
    u32* __restrict__ ax16) {
  const int l = threadIdx.x & 63;
  const int node = blockIdx.x * 4 + (threadIdx.x >> 6);
  const int e0 = row_start[node], e1 = row_start[node + 1];
  const float dn = dinv[node];
  const u32 vs = xbf[(size_t)node * 64 + l];
  float a0 = blo(vs) * (dn * dn);
  float a1 = bhi(vs) * (dn * dn);
  int e = e0;
  for (; e + 8 <= e1; e += 8) {
    const int2 E0 = edges[e], E1 = edges[e + 1], E2 = edges[e + 2], E3 = edges[e + 3];
    const int2 E4 = edges[e + 4], E5 = edges[e + 5], E6 = edges[e + 6], E7 = edges[e + 7];
    const u32 v0 = xbf[(size_t)E0.x * 64 + l];
    const u32 v1 = xbf[(size_t)E1.x * 64 + l];
    const u32 v2 = xbf[(size_t)E2.x * 64 + l];
    const u32 v3 = xbf[(size_t)E3.x * 64 + l];
    const u32 v4 = xbf[(size_t)E4.x * 64 + l];
    const u32 v5 = xbf[(size_t)E5.x * 64 + l];
    const u32 v6 = xbf[(size_t)E6.x * 64 + l];
    const u32 v7 = xbf[(size_t)E7.x * 64 + l];
    const float w0 = __int_as_float(E0.y), w1 = __int_as_float(E1.y);
    const float w2 = __int_as_float(E2.y), w3 = __int_as_float(E3.y);
    const float w4 = __int_as_float(E4.y), w5 = __int_as_float(E5.y);
    const float w6 = __int_as_float(E6.y), w7 = __int_as_float(E7.y);
    a0 = fmaf(blo(v0), w0, a0); a1 = fmaf(bhi(v0), w0, a1);
    a0 = fmaf(blo(v1), w1, a0); a1 = fmaf(bhi(v1), w1, a1);
    a0 = fmaf(blo(v2), w2, a0); a1 = fmaf(bhi(v2), w2, a1);
    a0 = fmaf(blo(v3), w3, a0); a1 = fmaf(bhi(v3), w3, a1);
    a0 = fmaf(blo(v4), w4, a0); a1 = fmaf(bhi(v4), w4, a1);
    a0 = fmaf(blo(v5), w5, a0); a1 = fmaf(bhi(v5), w5, a1);
    a0 = fmaf(blo(v6), w6, a0); a1 = fmaf(bhi(v6), w6, a1);
    a0 = fmaf(blo(v7), w7, a0); a1 = fmaf(bhi(v7), w7, a1);
  }
  for (; e < e1; ++e) {
    const int2 E = edges[e];
    const float w = __int_as_float(E.y);
    const u32 v = xbf[(size_t)E.x * 64 + l];
    a0 = fmaf(blo(v), w, a0);
    a1 = fmaf(bhi(v), w, a1);
  }
  // pack to f16 (RNE via casts)
  ax16[(size_t)node * 64 + l] = (u32)f2h(a0) | ((u32)f2h(a1) << 16);
}

// ---------- GEMM via MFMA f16: h16 = ax16 @ W16^T ----------
// Wave = 16 nodes x all 128 outs. A-frag: lane l = row (l&15), k-chunk
// (l>>4)*8, 8 contiguous f16. B-frag: lane l = col/out (l&15), same k
// chunking (reads W rows contiguously). D: col=lane&15, row=(lane>>4)*4+reg
// (m89-verified C/D layout).
__global__ __launch_bounds__(256) void gemm_mfma(const u32* __restrict__ ax16,
                                                 const u32* __restrict__ W16,
                                                 __fp16* __restrict__ h16) {
  const int wv = threadIdx.x >> 6;
  const int l = threadIdx.x & 63;
  const int m0 = (blockIdx.x * 4 + wv) * 16;
  if (m0 >= NN) return;
  const int rc = l & 15, kb = l >> 4;
  uint4 a[4];
#pragma unroll
  for (int s = 0; s < 4; ++s)
    a[s] = *(const uint4*)&ax16[(size_t)(m0 + rc) * 64 + s * 16 + kb * 4];
  f32x4 acc[8];
#pragma unroll
  for (int t = 0; t < 8; ++t) acc[t] = (f32x4){0.f, 0.f, 0.f, 0.f};
#pragma unroll
  for (int t = 0; t < 8; ++t) {
#pragma unroll
    for (int s = 0; s < 4; ++s) {
      uint4 b = *(const uint4*)&W16[(size_t)(t * 16 + rc) * 64 + s * 16 + kb * 4];
      acc[t] = __builtin_amdgcn_mfma_f32_16x16x32_f16(as_half8(a[s]), as_half8(b),
                                                      acc[t], 0, 0, 0);
    }
  }
#pragma unroll
  for (int t = 0; t < 8; ++t) {
#pragma unroll
    for (int r = 0; r < 4; ++r) {
      h16[(size_t)(m0 + kb * 4 + r) * C + t * 16 + rc] = (__fp16)acc[t][r];
    }
  }
}

// ---------- kan0f: h16 -> hid via v_dot2_f32_f16 ----------
__global__ __launch_bounds__(512) void kan0f(
    const __fp16* __restrict__ h16, const float* __restrict__ bias,
    const u16* __restrict__ p0h, float* __restrict__ hid) {
  __shared__ u32 P0s[8192];   // 32 KB: uint4 record J*128 + f  (8 f16 each)
  const int tid = threadIdx.x;
  {
    const uint4* g0 = (const uint4*)p0h;
    uint4* s0 = (uint4*)P0s;
    for (int r = tid; r < 2048; r += 512) s0[r] = g0[r];
  }
  __syncthreads();
  const int o = tid & 63;
  const int wave = tid >> 6;
  const float bLo = bias[o], bHi = bias[o + 64];
  const bool b1 = (o & 1), b2 = (o & 2), b4 = (o & 4), b8 = (o & 8);
  const int stride = gridDim.x * 8;
  for (int pr = blockIdx.x * 8 + wave; pr < NN / 2; pr += stride) {
    const int nodeA = pr * 2, nodeB = nodeA + 1;
    float t0, t1, t2, t3, t4, t5, t6, t7;
    feat8s((float)h16[(size_t)nodeA * C + o] + bLo, t0, t1, t2, t3, t4, t5, t6, t7);
    h2 aA0 = PK(t0, t1), aA1 = PK(t2, t3), aA2 = PK(t4, t5), aA3 = PK(t6, t7);
    feat8s((float)h16[(size_t)nodeA * C + o + 64] + bHi, t0, t1, t2, t3, t4, t5, t6, t7);
    h2 bA0 = PK(t0, t1), bA1 = PK(t2, t3), bA2 = PK(t4, t5), bA3 = PK(t6, t7);
    feat8s((float)h16[(size_t)nodeB * C + o] + bLo, t0, t1, t2, t3, t4, t5, t6, t7);
    h2 aB0 = PK(t0, t1), aB1 = PK(t2, t3), aB2 = PK(t4, t5), aB3 = PK(t6, t7);
    feat8s((float)h16[(size_t)nodeB * C + o + 64] + bHi, t0, t1, t2, t3, t4, t5, t6, t7);
    h2 bB0 = PK(t0, t1), bB1 = PK(t2, t3), bB2 = PK(t4, t5), bB3 = PK(t6, t7);
#define K0J(J)                                                                 \
    float pA##J, pB##J;                                                        \
    {                                                                          \
      uint4 ra = *(const uint4*)&P0s[(J) * 512 + o * 4];                       \
      uint4 rb = *(const uint4*)&P0s[(J) * 512 + (o + 64) * 4];                \
      float vA = DOT2(as_h2(ra.x), aA0, 0.f);                                  \
      vA = DOT2(as_h2(ra.y), aA1, vA);                                         \
      vA = DOT2(as_h2(ra.z), aA2, vA);                                         \
      vA = DOT2(as_h2(ra.w), aA3, vA);                                         \
      vA = DOT2(as_h2(rb.x), bA0, vA);                                         \
      vA = DOT2(as_h2(rb.y), bA1, vA);                                         \
      vA = DOT2(as_h2(rb.z), bA2, vA);                                         \
      pA##J = DOT2(as_h2(rb.w), bA3, vA);                                      \
      float vB = DOT2(as_h2(ra.x), aB0, 0.f);                                  \
      vB = DOT2(as_h2(ra.y), aB1, vB);                                         \
      vB = DOT2(as_h2(ra.z), aB2, vB);                                         \
      vB = DOT2(as_h2(ra.w), aB3, vB);                                         \
      vB = DOT2(as_h2(rb.x), bB0, vB);                                         \
      vB = DOT2(as_h2(rb.y), bB1, vB);                                         \
      vB = DOT2(as_h2(rb.z), bB2, vB);                                         \
      pB##J = DOT2(as_h2(rb.w), bB3, vB);                                      \
      __builtin_amdgcn_sched_barrier(0);                                      \
    }
    REP16(K0J)
#undef K0J
#define BFLY(p0_, p1_, p2_, p3_, p4_, p5_, p6_, p7_, p8_, p9_, p10_, p11_,     \
             p12_, p13_, p14_, p15_, OUTV)                                     \
    {                                                                          \
      float q0 = (b1 ? p1_ : p0_) + __shfl_xor(b1 ? p0_ : p1_, 1, 64);         \
      float q1 = (b1 ? p3_ : p2_) + __shfl_xor(b1 ? p2_ : p3_, 1, 64);         \
      float q2 = (b1 ? p5_ : p4_) + __shfl_xor(b1 ? p4_ : p5_, 1, 64);         \
      float q3 = (b1 ? p7_ : p6_) + __shfl_xor(b1 ? p6_ : p7_, 1, 64);         \
      float q4 = (b1 ? p9_ : p8_) + __shfl_xor(b1 ? p8_ : p9_, 1, 64);         \
      float q5 = (b1 ? p11_ : p10_) + __shfl_xor(b1 ? p10_ : p11_, 1, 64);     \
      float q6 = (b1 ? p13_ : p12_) + __shfl_xor(b1 ? p12_ : p13_, 1, 64);     \
      float q7 = (b1 ? p15_ : p14_) + __shfl_xor(b1 ? p14_ : p15_, 1, 64);     \
      float r0 = (b2 ? q1 : q0) + __shfl_xor(b2 ? q0 : q1, 2, 64);             \
      float r1 = (b2 ? q3 : q2) + __shfl_xor(b2 ? q2 : q3, 2, 64);             \
      float r2 = (b2 ? q5 : q4) + __shfl_xor(b2 ? q4 : q5, 2, 64);             \
      float r3 = (b2 ? q7 : q6) + __shfl_xor(b2 ? q6 : q7, 2, 64);             \
      float s0 = (b4 ? r1 : r0) + __shfl_xor(b4 ? r0 : r1, 4, 64);             \
      float s1 = (b4 ? r3 : r2) + __shfl_xor(b4 ? r2 : r3, 4, 64);             \
      float t_ = (b8 ? s1 : s0) + __shfl_xor(b8 ? s0 : s1, 8, 64);             \
      t_ += __shfl_xor(t_, 16, 64);                                            \
      t_ += __shfl_xor(t_, 32, 64);                                            \
      OUTV = t_;                                                               \
    }
    float hA, hB;
    BFLY(pA0, pA1, pA2, pA3, pA4, pA5, pA6, pA7, pA8, pA9, pA10, pA11, pA12,
         pA13, pA14, pA15, hA)
    BFLY(pB0, pB1, pB2, pB3, pB4, pB5, pB6, pB7, pB8, pB9, pB10, pB11, pB12,
         pB13, pB14, pB15, hB)
#undef BFLY
    if (o < 16) {
      hid[nodeA * 16 + o] = hA;
      hid[nodeB * 16 + o] = hB;
    }
  }
}

// ---------- kan1f: hid -> out via v_dot2_f32_f16 ----------
__global__ __launch_bounds__(512) void kan1f(
    const float* __restrict__ hid, const u16* __restrict__ p1h,
    float* __restrict__ out) {
  __shared__ u32 P1s[8192];   // 32 KB: uint4 record J*128 + o (transposed)
  const int tid = threadIdx.x;
  {
    const uint4* g1 = (const uint4*)p1h;  // record r = o*16 + j
    uint4* s1 = (uint4*)P1s;
    for (int r = tid; r < 2048; r += 512) {
      int oo = r >> 4, j = r & 15;
      s1[j * 128 + oo] = g1[r];
    }
  }
  __syncthreads();
  const int o = tid & 63;
  const int wave = tid >> 6;
  const int j16 = o & 15;
  const int stride = gridDim.x * 8;
  for (int pr = blockIdx.x * 8 + wave; pr < NN / 2; pr += stride) {
    const int nodeA = pr * 2, nodeB = nodeA + 1;
    float t0, t1, t2, t3, t4, t5, t6, t7;
    feat8s(hid[nodeA * 16 + j16], t0, t1, t2, t3, t4, t5, t6, t7);
    u32 uA0 = as_u32(PK(t0, t1)), uA1 = as_u32(PK(t2, t3));
    u32 uA2 = as_u32(PK(t4, t5)), uA3 = as_u32(PK(t6, t7));
    feat8s(hid[nodeB * 16 + j16], t0, t1, t2, t3, t4, t5, t6, t7);
    u32 uB0 = as_u32(PK(t0, t1)), uB1 = as_u32(PK(t2, t3));
    u32 uB2 = as_u32(PK(t4, t5)), uB3 = as_u32(PK(t6, t7));
    float accLoA = 0.f, accHiA = 0.f, accLoB = 0.f, accHiB = 0.f;
#define K1J(J)                                                                 \
    {                                                                          \
      uint4 ra = *(const uint4*)&P1s[(J) * 512 + o * 4];                       \
      uint4 rb = *(const uint4*)&P1s[(J) * 512 + (o + 64) * 4];                \
      h2 qA0 = as_h2(RLU(uA0, J)), qA1 = as_h2(RLU(uA1, J));                   \
      h2 qA2 = as_h2(RLU(uA2, J)), qA3 = as_h2(RLU(uA3, J));                   \
      h2 qB0 = as_h2(RLU(uB0, J)), qB1 = as_h2(RLU(uB1, J));                   \
      h2 qB2 = as_h2(RLU(uB2, J)), qB3 = as_h2(RLU(uB3, J));                   \
      accLoA = DOT2(as_h2(ra.x), qA0, accLoA);                                 \
      accLoA = DOT2(as_h2(ra.y), qA1, accLoA);                                 \
      accLoA = DOT2(as_h2(ra.z), qA2, accLoA);                                 \
      accLoA = DOT2(as_h2(ra.w), qA3, accLoA);                                 \
      accHiA = DOT2(as_h2(rb.x), qA0, accHiA);                                 \
      accHiA = DOT2(as_h2(rb.y), qA1, accHiA);                                 \
      accHiA = DOT2(as_h2(rb.z), qA2, accHiA);                                 \
      accHiA = DOT2(as_h2(rb.w), qA3, accHiA);                                 \
      accLoB = DOT2(as_h2(ra.x), qB0, accLoB);                                 \
      accLoB = DOT2(as_h2(ra.y), qB1, accLoB);                                 \
      accLoB = DOT2(as_h2(ra.z), qB2, accLoB);                                 \
      accLoB = DOT2(as_h2(ra.w), qB3, accLoB);                                 \
      accHiB = DOT2(as_h2(rb.x), qB0, accHiB);                                 \
      accHiB = DOT2(as_h2(rb.y), qB1, accHiB);                                 \
      accHiB = DOT2(as_h2(rb.z), qB2, accHiB);                                 \
      accHiB = DOT2(as_h2(rb.w), qB3, accHiB);                                 \
      __builtin_amdgcn_sched_barrier(0);                                      \
    }
    REP16(K1J)
#undef K1J
    out[(size_t)nodeA * C + o] = accLoA;
    out[(size_t)nodeA * C + o + 64] = accHiA;
    out[(size_t)nodeB * C + o] = accLoB;
    out[(size_t)nodeB * C + o + 64] = accHiB;
  }
}

extern "C" void kernel_launch(void* const* d_in, const int* in_sizes, int n_in,
                              void* d_out, int out_size, void* d_ws, size_t ws_size,
                              hipStream_t stream) {
  const float* x   = (const float*)d_in[0];
  const int*   ei  = (const int*)d_in[1];
  const float* gw  = (const float*)d_in[2];
  const float* gb  = (const float*)d_in[3];
  const float* bw0 = (const float*)d_in[4];
  const float* sw0 = (const float*)d_in[5];
  const float* sc0 = (const float*)d_in[6];
  const float* bw1 = (const float*)d_in[7];
  const float* sw1 = (const float*)d_in[8];
  const float* sc1 = (const float*)d_in[9];
  float* out = (float*)d_out;

  char* p = (char*)d_ws;
  u32* W16 = (u32*)p;         p += C * C * 2;            // 32 KB f16 packed
  u16* p0h = (u16*)p;         p += H * C * 8 * 2;        // 32 KB
  u16* p1h = (u16*)p;         p += C * H * 8 * 2;        // 32 KB
  float* dinv = (float*)p;    p += NN * 4;
  int* cnt = (int*)p;         p += NN * 4;               // cnt+fillcnt adjacent
  int* fillcnt = (int*)p;     p += NN * 4;
  int* excl = (int*)p;        p += NN * 4;
  int* bsums = (int*)p;       p += 256 * 4;
  int* row_start = (int*)p;   p += (NN + 4) * 4;
  float* hid = (float*)p;     p += (size_t)NN * H * 4;   // 3.2 MB
  u32* xbf = (u32*)p;         p += (size_t)NN * C * 2;   // 12.8 MB
  int2* edges = (int2*)p;     p += (size_t)NE * 8;       // 6.4 MB
  u32* ax16 = (u32*)p;        p += (size_t)NN * C * 2;   // 12.8 MB
  __fp16* h16 = (__fp16*)p;   p += (size_t)NN * C * 2;   // 12.8 MB

  const int* src = ei;
  const int* dst = ei + NE;

  hipMemsetAsync(cnt, 0, 2 * NN * 4, stream);

  prep_kernel<<<6250, 256, 0, stream>>>(gw, bw0, sw0, sc0, bw1, sw1, sc1, x,
                                        W16, p0h, p1h, xbf);
  count_kernel<<<(NE + 255) / 256, 256, 0, stream>>>(dst, cnt);
  scan1<<<196, 256, 0, stream>>>(cnt, excl, bsums, NN);
  scan3<<<196, 256, 0, stream>>>(excl, bsums, cnt, row_start, dinv, NN, 196);
  fill_kernel<<<(NE + 255) / 256, 256, 0, stream>>>(src, dst, row_start, dinv, fillcnt, edges);
  agg_kernel<<<NN / 4, 256, 0, stream>>>(xbf, edges, row_start, dinv, ax16);
  gemm_mfma<<<(NN + 63) / 64, 256, 0, stream>>>(ax16, W16, h16);
  kan0f<<<1024, 512, 0, stream>>>(h16, gb, p0h, hid);
  kan1f<<<1024, 512, 0, stream>>>(hid, p1h, out);
}

// Round 15
// 204.457 us; speedup vs baseline: 4.1276x; 1.1309x over previous
//
#include <hip/hip_runtime.h>

#define NN 50000
#define NE 800000
#define C 128
#define H 16

typedef unsigned int u32;
typedef unsigned short u16;
typedef __fp16 h2 __attribute__((ext_vector_type(2)));
typedef __fp16 half8 __attribute__((ext_vector_type(8)));
typedef float f32x4 __attribute__((ext_vector_type(4)));

__device__ __forceinline__ h2 as_h2(u32 v) {
  union { u32 u; h2 h; } c; c.u = v; return c.h;
}
__device__ __forceinline__ u32 as_u32(h2 h) {
  union { u32 u; h2 h; } c; c.h = h; return c.u;
}
__device__ __forceinline__ half8 as_half8(uint4 v) {
  union { uint4 u; half8 h; } c; c.u = v; return c.h;
}
#define PK(a, b) __builtin_amdgcn_cvt_pkrtz((a), (b))
#define DOT2(w, f, acc) __builtin_amdgcn_fdot2((w), (f), (acc), false)

// ---------- silu + 7 cubic B-spline bases, closed form, NAMED outputs ----------
__device__ __forceinline__ void feat8s(float x, float& s, float& g0, float& g1,
                                       float& g2, float& g3, float& g4, float& g5,
                                       float& g6) {
  s = x / (1.f + __expf(-x));
  float t = (x + 2.5f) * 2.0f;
  float cf = floorf(t);
  int c = (int)cf;
  float u = t - cf;
  float u2 = u * u, u3 = u2 * u;
  const float k6 = 1.f / 6.f;
  float P0 = u3 * k6;
  float P1 = (1.f + 3.f * u + 3.f * u2 - 3.f * u3) * k6;
  float P2 = (4.f - 6.f * u2 + 3.f * u3) * k6;
  float om = 1.f - u;
  float P3 = om * om * om * k6;
  bool valid = (t >= 0.f) && (t < 10.f);
#define SPJ(G, J)                                   \
  {                                                 \
    float b = 0.f;                                  \
    b = (c == (J)) ? P0 : b;                        \
    b = (c == (J) + 1) ? P1 : b;                    \
    b = (c == (J) + 2) ? P2 : b;                    \
    b = (c == (J) + 3) ? P3 : b;                    \
    G = valid ? b : 0.f;                            \
  }
  SPJ(g0, 0) SPJ(g1, 1) SPJ(g2, 2) SPJ(g3, 3) SPJ(g4, 4) SPJ(g5, 5) SPJ(g6, 6)
#undef SPJ
}

__device__ __forceinline__ u16 f2bf(float v) {
  u32 b = __float_as_uint(v);
  return (u16)((b + 0x7fffu + ((b >> 16) & 1u)) >> 16);  // RNE
}
__device__ __forceinline__ u16 f2h(float v) {
  union { __fp16 h; u16 u; } c; c.h = (__fp16)v; return c.u;
}
__device__ __forceinline__ float blo(u32 v) { return __uint_as_float(v << 16); }
__device__ __forceinline__ float bhi(u32 v) { return __uint_as_float(v & 0xffff0000u); }

#define RLU(x, J) ((u32)__builtin_amdgcn_readlane((int)(x), (J)))
#define REP16(M) M(0) M(1) M(2) M(3) M(4) M(5) M(6) M(7) M(8) M(9) M(10) M(11) M(12) M(13) M(14) M(15)

// ---------- prep_w: f16 W + f16 KAN weights (16384 threads cover all) ----------
__global__ void prep_w(const float* __restrict__ W,
                       const float* __restrict__ bw0, const float* __restrict__ sw0,
                       const float* __restrict__ sc0,
                       const float* __restrict__ bw1, const float* __restrict__ sw1,
                       const float* __restrict__ sc1,
                       u32* __restrict__ W16, u16* __restrict__ p0h,
                       u16* __restrict__ p1h) {
  int i = blockIdx.x * blockDim.x + threadIdx.x;
  if (i < C * C / 2) {  // W row-major, packed f16 pairs along k
    int o = i >> 6, kp = i & 63;
    W16[i] = (u32)f2h(W[o * C + kp * 2]) | ((u32)f2h(W[o * C + kp * 2 + 1]) << 16);
  }
  if (i < H * C * 8) {
    int of = i >> 3, j = i & 7;
    float v = (j == 0) ? bw0[of] : sw0[of * 7 + (j - 1)] * sc0[of];
    p0h[i] = f2h(v);
  }
  if (i < C * H * 8) {
    int of = i >> 3, j = i & 7;
    float v = (j == 0) ? bw1[of] : sw1[of * 7 + (j - 1)] * sc1[of];
    p1h[i] = f2h(v);
  }
}

// ---------- count + slot capture ----------
__global__ void count_kernel(const int* __restrict__ dst, int* __restrict__ cnt,
                             int* __restrict__ slot) {
  int e = blockIdx.x * blockDim.x + threadIdx.x;
  if (e < NE) slot[e] = atomicAdd(&cnt[dst[e]], 1);
}

// ---------- scan1: block-local exclusive scan + block totals ----------
__global__ void scan1(const int* __restrict__ cnt, int* __restrict__ excl,
                      int* __restrict__ bsums, int n) {
  int i = blockIdx.x * 256 + threadIdx.x;
  int v = (i < n) ? cnt[i] : 0;
  int lane = threadIdx.x & 63, wid = threadIdx.x >> 6;
  int s = v;
#pragma unroll
  for (int o = 1; o < 64; o <<= 1) {
    int t = __shfl_up(s, o, 64);
    if (lane >= o) s += t;
  }
  __shared__ int wsum[4];
  if (lane == 63) wsum[wid] = s;
  __syncthreads();
  int woff = 0;
  for (int w = 0; w < wid; ++w) woff += wsum[w];
  if (i < n) excl[i] = woff + s - v;
  if (threadIdx.x == 255) bsums[blockIdx.x] = woff + s;
}

// ---------- scan3 (scan2 folded in) ----------
__global__ void scan3(const int* __restrict__ excl, const int* __restrict__ bsums,
                      const int* __restrict__ cnt, int* __restrict__ row_start,
                      float* __restrict__ dinv, int n, int nb) {
  __shared__ int red[256];
  const int t = threadIdx.x;
  red[t] = (t < nb && t < (int)blockIdx.x) ? bsums[t] : 0;
  __syncthreads();
#pragma unroll
  for (int s = 128; s > 0; s >>= 1) {
    if (t < s) red[t] += red[t + s];
    __syncthreads();
  }
  const int boff = red[0];
  const int i = blockIdx.x * 256 + t;
  if (i < n) {
    row_start[i] = excl[i] + boff;
    dinv[i] = rsqrtf((float)(cnt[i] + 1));
  }
  if (blockIdx.x == 0 && t == 0) row_start[n] = NE;
}

// ---------- xs_prep: xs[n][c] = bf16(x[n][c] * dinv[n]) packed ----------
__global__ void xs_prep(const float* __restrict__ x, const float* __restrict__ dinv,
                        u32* __restrict__ xs) {
  int i = blockIdx.x * blockDim.x + threadIdx.x;  // one float4 per thread
  if (i < NN * C / 4) {
    int n = i >> 5;  // 32 float4 per row
    float dv = dinv[n];
    float4 v = *(const float4*)&x[(size_t)i * 4];
    u32 lo = (u32)f2bf(v.x * dv) | ((u32)f2bf(v.y * dv) << 16);
    u32 hi = (u32)f2bf(v.z * dv) | ((u32)f2bf(v.w * dv) << 16);
    *(uint2*)&xs[(size_t)i * 2] = make_uint2(lo, hi);
  }
}

// ---------- CSR fill: atomic-free 4B scatter per edge ----------
__global__ void fill_kernel(const int* __restrict__ src, const int* __restrict__ dst,
                            const int* __restrict__ slot,
                            const int* __restrict__ row_start, int* __restrict__ csr) {
  int e = blockIdx.x * blockDim.x + threadIdx.x;
  if (e < NE) csr[row_start[dst[e]] + slot[e]] = src[e];
}

// ---------- aggregation: pure gather+add (weights pre-folded), f16 out ----------
__global__ __launch_bounds__(256, 8) void agg_kernel(
    const u32* __restrict__ xs, const int* __restrict__ csr,
    const int* __restrict__ row_start, const float* __restrict__ dinv,
    u32* __restrict__ ax16) {
  const int l = threadIdx.x & 63;
  const int node = blockIdx.x * 4 + (threadIdx.x >> 6);
  const int e0 = row_start[node], e1 = row_start[node + 1];
  const float dn = dinv[node];
  const u32 vs = xs[(size_t)node * 64 + l];
  float a0 = blo(vs), a1 = bhi(vs);
  int e = e0;
  for (; e + 8 <= e1; e += 8) {
    const int s0 = csr[e], s1 = csr[e + 1], s2 = csr[e + 2], s3 = csr[e + 3];
    const int s4 = csr[e + 4], s5 = csr[e + 5], s6 = csr[e + 6], s7 = csr[e + 7];
    const u32 v0 = xs[(size_t)s0 * 64 + l];
    const u32 v1 = xs[(size_t)s1 * 64 + l];
    const u32 v2 = xs[(size_t)s2 * 64 + l];
    const u32 v3 = xs[(size_t)s3 * 64 + l];
    const u32 v4 = xs[(size_t)s4 * 64 + l];
    const u32 v5 = xs[(size_t)s5 * 64 + l];
    const u32 v6 = xs[(size_t)s6 * 64 + l];
    const u32 v7 = xs[(size_t)s7 * 64 + l];
    a0 += blo(v0); a1 += bhi(v0);
    a0 += blo(v1); a1 += bhi(v1);
    a0 += blo(v2); a1 += bhi(v2);
    a0 += blo(v3); a1 += bhi(v3);
    a0 += blo(v4); a1 += bhi(v4);
    a0 += blo(v5); a1 += bhi(v5);
    a0 += blo(v6); a1 += bhi(v6);
    a0 += blo(v7); a1 += bhi(v7);
  }
  for (; e < e1; ++e) {
    const u32 v = xs[(size_t)csr[e] * 64 + l];
    a0 += blo(v);
    a1 += bhi(v);
  }
  a0 *= dn;
  a1 *= dn;
  ax16[(size_t)node * 64 + l] = (u32)f2h(a0) | ((u32)f2h(a1) << 16);
}

// ---------- GEMM via MFMA f16: h16 = ax16 @ W16^T (r14-verified layout) ----------
__global__ __launch_bounds__(256) void gemm_mfma(const u32* __restrict__ ax16,
                                                 const u32* __restrict__ W16,
                                                 __fp16* __restrict__ h16) {
  const int wv = threadIdx.x >> 6;
  const int l = threadIdx.x & 63;
  const int m0 = (blockIdx.x * 4 + wv) * 16;
  if (m0 >= NN) return;
  const int rc = l & 15, kb = l >> 4;
  uint4 a[4];
#pragma unroll
  for (int s = 0; s < 4; ++s)
    a[s] = *(const uint4*)&ax16[(size_t)(m0 + rc) * 64 + s * 16 + kb * 4];
  f32x4 acc[8];
#pragma unroll
  for (int t = 0; t < 8; ++t) acc[t] = (f32x4){0.f, 0.f, 0.f, 0.f};
#pragma unroll
  for (int t = 0; t < 8; ++t) {
#pragma unroll
    for (int s = 0; s < 4; ++s) {
      uint4 b = *(const uint4*)&W16[(size_t)(t * 16 + rc) * 64 + s * 16 + kb * 4];
      acc[t] = __builtin_amdgcn_mfma_f32_16x16x32_f16(as_half8(a[s]), as_half8(b),
                                                      acc[t], 0, 0, 0);
    }
  }
#pragma unroll
  for (int t = 0; t < 8; ++t) {
#pragma unroll
    for (int r = 0; r < 4; ++r) {
      h16[(size_t)(m0 + kb * 4 + r) * C + t * 16 + rc] = (__fp16)acc[t][r];
    }
  }
}

// ---------- kanF: merged KAN0+KAN1 (hA stays in registers between layers) ----------
__global__ __launch_bounds__(512) void kanF(
    const __fp16* __restrict__ h16, const float* __restrict__ bias,
    const u16* __restrict__ p0h, const u16* __restrict__ p1h,
    float* __restrict__ out) {
  __shared__ u32 P0s[8192];   // 32 KB: uint4 record J*128 + f
  __shared__ u32 P1s[8192];   // 32 KB: uint4 record J*128 + o (transposed)
  const int tid = threadIdx.x;
  {
    const uint4* g0 = (const uint4*)p0h;
    const uint4* g1 = (const uint4*)p1h;
    uint4* s0 = (uint4*)P0s;
    uint4* s1 = (uint4*)P1s;
    for (int r = tid; r < 2048; r += 512) {
      s0[r] = g0[r];
      int oo = r >> 4, j = r & 15;
      s1[j * 128 + oo] = g1[r];
    }
  }
  __syncthreads();
  const int o = tid & 63;
  const int wave = tid >> 6;
  const float bLo = bias[o], bHi = bias[o + 64];
  const bool b1 = (o & 1), b2 = (o & 2), b4 = (o & 4), b8 = (o & 8);
  const int stride = gridDim.x * 8;
  for (int pr = blockIdx.x * 8 + wave; pr < NN / 2; pr += stride) {
    const int nodeA = pr * 2, nodeB = nodeA + 1;
    float t0, t1, t2, t3, t4, t5, t6, t7;
    feat8s((float)h16[(size_t)nodeA * C + o] + bLo, t0, t1, t2, t3, t4, t5, t6, t7);
    h2 aA0 = PK(t0, t1), aA1 = PK(t2, t3), aA2 = PK(t4, t5), aA3 = PK(t6, t7);
    feat8s((float)h16[(size_t)nodeA * C + o + 64] + bHi, t0, t1, t2, t3, t4, t5, t6, t7);
    h2 bA0 = PK(t0, t1), bA1 = PK(t2, t3), bA2 = PK(t4, t5), bA3 = PK(t6, t7);
    feat8s((float)h16[(size_t)nodeB * C + o] + bLo, t0, t1, t2, t3, t4, t5, t6, t7);
    h2 aB0 = PK(t0, t1), aB1 = PK(t2, t3), aB2 = PK(t4, t5), aB3 = PK(t6, t7);
    feat8s((float)h16[(size_t)nodeB * C + o + 64] + bHi, t0, t1, t2, t3, t4, t5, t6, t7);
    h2 bB0 = PK(t0, t1), bB1 = PK(t2, t3), bB2 = PK(t4, t5), bB3 = PK(t6, t7);
#define K0J(J)                                                                 \
    float pA##J, pB##J;                                                        \
    {                                                                          \
      uint4 ra = *(const uint4*)&P0s[(J) * 512 + o * 4];                       \
      uint4 rb = *(const uint4*)&P0s[(J) * 512 + (o + 64) * 4];                \
      float vA = DOT2(as_h2(ra.x), aA0, 0.f);                                  \
      vA = DOT2(as_h2(ra.y), aA1, vA);                                         \
      vA = DOT2(as_h2(ra.z), aA2, vA);                                         \
      vA = DOT2(as_h2(ra.w), aA3, vA);                                         \
      vA = DOT2(as_h2(rb.x), bA0, vA);                                         \
      vA = DOT2(as_h2(rb.y), bA1, vA);                                         \
      vA = DOT2(as_h2(rb.z), bA2, vA);                                         \
      pA##J = DOT2(as_h2(rb.w), bA3, vA);                                      \
      float vB = DOT2(as_h2(ra.x), aB0, 0.f);                                  \
      vB = DOT2(as_h2(ra.y), aB1, vB);                                         \
      vB = DOT2(as_h2(ra.z), aB2, vB);                                         \
      vB = DOT2(as_h2(ra.w), aB3, vB);                                         \
      vB = DOT2(as_h2(rb.x), bB0, vB);                                         \
      vB = DOT2(as_h2(rb.y), bB1, vB);                                         \
      vB = DOT2(as_h2(rb.z), bB2, vB);                                         \
      pB##J = DOT2(as_h2(rb.w), bB3, vB);                                      \
      __builtin_amdgcn_sched_barrier(0);                                      \
    }
    REP16(K0J)
#undef K0J
#define BFLY(p0_, p1_, p2_, p3_, p4_, p5_, p6_, p7_, p8_, p9_, p10_, p11_,     \
             p12_, p13_, p14_, p15_, OUTV)                                     \
    {                                                                          \
      float q0 = (b1 ? p1_ : p0_) + __shfl_xor(b1 ? p0_ : p1_, 1, 64);         \
      float q1 = (b1 ? p3_ : p2_) + __shfl_xor(b1 ? p2_ : p3_, 1, 64);         \
      float q2 = (b1 ? p5_ : p4_) + __shfl_xor(b1 ? p4_ : p5_, 1, 64);         \
      float q3 = (b1 ? p7_ : p6_) + __shfl_xor(b1 ? p6_ : p7_, 1, 64);         \
      float q4 = (b1 ? p9_ : p8_) + __shfl_xor(b1 ? p8_ : p9_, 1, 64);         \
      float q5 = (b1 ? p11_ : p10_) + __shfl_xor(b1 ? p10_ : p11_, 1, 64);     \
      float q6 = (b1 ? p13_ : p12_) + __shfl_xor(b1 ? p12_ : p13_, 1, 64);     \
      float q7 = (b1 ? p15_ : p14_) + __shfl_xor(b1 ? p14_ : p15_, 1, 64);     \
      float r0 = (b2 ? q1 : q0) + __shfl_xor(b2 ? q0 : q1, 2, 64);             \
      float r1 = (b2 ? q3 : q2) + __shfl_xor(b2 ? q2 : q3, 2, 64);             \
      float r2 = (b2 ? q5 : q4) + __shfl_xor(b2 ? q4 : q5, 2, 64);             \
      float r3 = (b2 ? q7 : q6) + __shfl_xor(b2 ? q6 : q7, 2, 64);             \
      float s0 = (b4 ? r1 : r0) + __shfl_xor(b4 ? r0 : r1, 4, 64);             \
      float s1 = (b4 ? r3 : r2) + __shfl_xor(b4 ? r2 : r3, 4, 64);             \
      float t_ = (b8 ? s1 : s0) + __shfl_xor(b8 ? s0 : s1, 8, 64);             \
      t_ += __shfl_xor(t_, 16, 64);                                            \
      t_ += __shfl_xor(t_, 32, 64);                                            \
      OUTV = t_;                                                               \
    }
    float hA, hB;
    BFLY(pA0, pA1, pA2, pA3, pA4, pA5, pA6, pA7, pA8, pA9, pA10, pA11, pA12,
         pA13, pA14, pA15, hA)
    BFLY(pB0, pB1, pB2, pB3, pB4, pB5, pB6, pB7, pB8, pB9, pB10, pB11, pB12,
         pB13, pB14, pB15, hB)
#undef BFLY
    // lane o holds hidden value j16 = o&15 for both nodes -> straight into KAN1
    feat8s(hA, t0, t1, t2, t3, t4, t5, t6, t7);
    u32 uA0 = as_u32(PK(t0, t1)), uA1 = as_u32(PK(t2, t3));
    u32 uA2 = as_u32(PK(t4, t5)), uA3 = as_u32(PK(t6, t7));
    feat8s(hB, t0, t1, t2, t3, t4, t5, t6, t7);
    u32 uB0 = as_u32(PK(t0, t1)), uB1 = as_u32(PK(t2, t3));
    u32 uB2 = as_u32(PK(t4, t5)), uB3 = as_u32(PK(t6, t7));
    float accLoA = 0.f, accHiA = 0.f, accLoB = 0.f, accHiB = 0.f;
#define K1J(J)                                                                 \
    {                                                                          \
      uint4 ra = *(const uint4*)&P1s[(J) * 512 + o * 4];                       \
      uint4 rb = *(const uint4*)&P1s[(J) * 512 + (o + 64) * 4];                \
      h2 qA0 = as_h2(RLU(uA0, J)), qA1 = as_h2(RLU(uA1, J));                   \
      h2 qA2 = as_h2(RLU(uA2, J)), qA3 = as_h2(RLU(uA3, J));                   \
      h2 qB0 = as_h2(RLU(uB0, J)), qB1 = as_h2(RLU(uB1, J));                   \
      h2 qB2 = as_h2(RLU(uB2, J)), qB3 = as_h2(RLU(uB3, J));                   \
      accLoA = DOT2(as_h2(ra.x), qA0, accLoA);                                 \
      accLoA = DOT2(as_h2(ra.y), qA1, accLoA);                                 \
      accLoA = DOT2(as_h2(ra.z), qA2, accLoA);                                 \
      accLoA = DOT2(as_h2(ra.w), qA3, accLoA);                                 \
      accHiA = DOT2(as_h2(rb.x), qA0, accHiA);                                 \
      accHiA = DOT2(as_h2(rb.y), qA1, accHiA);                                 \
      accHiA = DOT2(as_h2(rb.z), qA2, accHiA);                                 \
      accHiA = DOT2(as_h2(rb.w), qA3, accHiA);                                 \
      accLoB = DOT2(as_h2(ra.x), qB0, accLoB);                                 \
      accLoB = DOT2(as_h2(ra.y), qB1, accLoB);                                 \
      accLoB = DOT2(as_h2(ra.z), qB2, accLoB);                                 \
      accLoB = DOT2(as_h2(ra.w), qB3, accLoB);                                 \
      accHiB = DOT2(as_h2(rb.x), qB0, accHiB);                                 \
      accHiB = DOT2(as_h2(rb.y), qB1, accHiB);                                 \
      accHiB = DOT2(as_h2(rb.z), qB2, accHiB);                                 \
      accHiB = DOT2(as_h2(rb.w), qB3, accHiB);                                 \
      __builtin_amdgcn_sched_barrier(0);                                      \
    }
    REP16(K1J)
#undef K1J
    out[(size_t)nodeA * C + o] = accLoA;
    out[(size_t)nodeA * C + o + 64] = accHiA;
    out[(size_t)nodeB * C + o] = accLoB;
    out[(size_t)nodeB * C + o + 64] = accHiB;
  }
}

extern "C" void kernel_launch(void* const* d_in, const int* in_sizes, int n_in,
                              void* d_out, int out_size, void* d_ws, size_t ws_size,
                              hipStream_t stream) {
  const float* x   = (const float*)d_in[0];
  const int*   ei  = (const int*)d_in[1];
  const float* gw  = (const float*)d_in[2];
  const float* gb  = (const float*)d_in[3];
  const float* bw0 = (const float*)d_in[4];
  const float* sw0 = (const float*)d_in[5];
  const float* sc0 = (const float*)d_in[6];
  const float* bw1 = (const float*)d_in[7];
  const float* sw1 = (const float*)d_in[8];
  const float* sc1 = (const float*)d_in[9];
  float* out = (float*)d_out;

  char* p = (char*)d_ws;
  u32* W16 = (u32*)p;         p += C * C * 2;            // 32 KB
  u16* p0h = (u16*)p;         p += H * C * 8 * 2;        // 32 KB
  u16* p1h = (u16*)p;         p += C * H * 8 * 2;        // 32 KB
  float* dinv = (float*)p;    p += NN * 4;
  int* cnt = (int*)p;         p += NN * 4;
  int* excl = (int*)p;        p += NN * 4;
  int* bsums = (int*)p;       p += 256 * 4;
  int* row_start = (int*)p;   p += (NN + 4) * 4;
  int* slot = (int*)p;        p += (size_t)NE * 4;       // 3.2 MB
  int* csr = (int*)p;         p += (size_t)NE * 4;       // 3.2 MB
  u32* xs = (u32*)p;          p += (size_t)NN * C * 2;   // 12.8 MB
  u32* ax16 = (u32*)p;        p += (size_t)NN * C * 2;   // 12.8 MB
  __fp16* h16 = (__fp16*)p;   p += (size_t)NN * C * 2;   // 12.8 MB

  const int* src = ei;
  const int* dst = ei + NE;

  hipMemsetAsync(cnt, 0, NN * 4, stream);

  prep_w<<<64, 256, 0, stream>>>(gw, bw0, sw0, sc0, bw1, sw1, sc1, W16, p0h, p1h);
  count_kernel<<<(NE + 255) / 256, 256, 0, stream>>>(dst, cnt, slot);
  scan1<<<196, 256, 0, stream>>>(cnt, excl, bsums, NN);
  scan3<<<196, 256, 0, stream>>>(excl, bsums, cnt, row_start, dinv, NN, 196);
  xs_prep<<<(NN * C / 4 + 255) / 256, 256, 0, stream>>>(x, dinv, xs);
  fill_kernel<<<(NE + 255) / 256, 256, 0, stream>>>(src, dst, slot, row_start, csr);
  agg_kernel<<<NN / 4, 256, 0, stream>>>(xs, csr, row_start, dinv, ax16);
  gemm_mfma<<<(NN + 63) / 64, 256, 0, stream>>>(ax16, W16, h16);
  kanF<<<512, 512, 0, stream>>>(h16, gb, p0h, p1h, out);
}